// Round 5
// baseline (728.290 us; speedup 1.0000x reference)
//
#include <hip/hip_runtime.h>
#include <hip/hip_bf16.h>

#define N_NODES 100000
#define N_EDGES 3200000
#define N_GRAPHS 256
#define SCAN1_BLKS 98       // 98*1024 = 100352 >= N_NODES

// ---------------- workspace layout (bytes) ----------------
#define OFF_SUMS      0u            // float[256*64] pool sums (zeroed in zero_kernel)
#define OFF_CNTF      65536u        // float[256] pool counts
#define OFF_DEG       66560u        // int[N] in-degree
#define ZERO_BYTES    466576u       // sums + cntf + deg all zeroed
#define OFF_BSUM2     466576u       // int[98] scan block sums (+pad)
#define OFF_ROWPTR    467088u       // int[N+1]
#define OFF_CURS      867104u       // int[N] scatter cursors
#define OFF_DINV      1267104u      // float[N]
#define OFF_COL       1667104u      // int[E]
#define OFF_XS1       14467104u     // bf16[N*8] (16B rows, 16-aligned)
#define OFF_BUFQ      20268544u     // bf16 xs2 [N*64], later fp32 z3 [N*64]
#define OFF_BUFR      45868544u     // bf16 z2 [N*64], later bf16 ys [N*64]
#define OFF_BUFP      71468544u     // bf16 h2 [N*128]
// total ~97.1 MB

// round-to-nearest-even float -> bf16 (values are finite; no NaN guard needed)
__device__ __forceinline__ unsigned short f2bf(float f) {
    unsigned u = __float_as_uint(f);
    return (unsigned short)((u + 0x7fffu + ((u >> 16) & 1u)) >> 16);
}

// unpack uint4 (8 bf16) and accumulate m * value into a[0..7] (fp32)
__device__ __forceinline__ void acc_bf8(uint4 v, float m, float* a) {
    a[0] += m * __uint_as_float(v.x << 16);
    a[1] += m * __uint_as_float(v.x & 0xffff0000u);
    a[2] += m * __uint_as_float(v.y << 16);
    a[3] += m * __uint_as_float(v.y & 0xffff0000u);
    a[4] += m * __uint_as_float(v.z << 16);
    a[5] += m * __uint_as_float(v.z & 0xffff0000u);
    a[6] += m * __uint_as_float(v.w << 16);
    a[7] += m * __uint_as_float(v.w & 0xffff0000u);
}

// ---- B0: zero pool accumulators + deg.
__global__ __launch_bounds__(256) void zero_kernel(int* __restrict__ zbase) {
    int gid = blockIdx.x * 256 + threadIdx.x;
    if (gid < (int)(ZERO_BYTES / 4)) zbase[gid] = 0;
}

// ---- B1: per-node in-degree. Fire-and-forget L2 atomics (no return value
// -> no wait); 400KB counter table is L2-resident, ~32 hits/counter.
__global__ __launch_bounds__(256) void deg_kernel(const int* __restrict__ dst,
                                                  int* __restrict__ deg, int E) {
    int stride = gridDim.x * 256;
    for (int e = blockIdx.x * 256 + threadIdx.x; e < E; e += stride)
        atomicAdd(&deg[__builtin_nontemporal_load(&dst[e])], 1);
}

// ---- B2: block-local exclusive scan of deg -> row_ptr, block sums out.
__global__ __launch_bounds__(1024) void scan1_kernel(const int* __restrict__ deg,
                                                     int* __restrict__ rp,
                                                     int* __restrict__ bsum, int n) {
    __shared__ int s[1024];
    int t = threadIdx.x;
    int i = blockIdx.x * 1024 + t;
    int v = (i < n) ? deg[i] : 0;
    s[t] = v;
    __syncthreads();
    for (int off = 1; off < 1024; off <<= 1) {
        int add = (t >= off) ? s[t - off] : 0;
        __syncthreads();
        s[t] += add;
        __syncthreads();
    }
    if (i < n) rp[i] = s[t] - v;           // block-local exclusive
    if (t == 1023) bsum[blockIdx.x] = s[t];
}

// ---- B3: exclusive scan of the 98 block sums (single block).
__global__ __launch_bounds__(128) void scan2_kernel(int* __restrict__ bsum) {
    __shared__ int s[128];
    int t = threadIdx.x;
    int v = (t < SCAN1_BLKS) ? bsum[t] : 0;
    s[t] = v;
    __syncthreads();
    for (int off = 1; off < 128; off <<= 1) {
        int add = (t >= off) ? s[t - off] : 0;
        __syncthreads();
        s[t] += add;
        __syncthreads();
    }
    if (t < SCAN1_BLKS) bsum[t] = s[t] - v;   // exclusive
}

// ---- B4: finalize row_ptr (+global offset), init cursors, dinv, xs1=bf16(dinv*x).
__global__ __launch_bounds__(1024) void fin_kernel(const int* __restrict__ bsum,
                                                   const int* __restrict__ deg,
                                                   const float* __restrict__ x,
                                                   int* __restrict__ rp,
                                                   int* __restrict__ cursor,
                                                   float* __restrict__ dinv,
                                                   unsigned short* __restrict__ xs1,
                                                   int n, int E) {
    int t = threadIdx.x, blk = blockIdx.x;
    int i = blk * 1024 + t;
    if (i < n) {
        int rpv = rp[i] + bsum[blk];
        rp[i] = rpv;
        cursor[i] = rpv;
        float d = rsqrtf((float)(deg[i] + 1));
        dinv[i] = d;
        const float4* xv = reinterpret_cast<const float4*>(x) + i * 2;
        float4 xa = xv[0], xb = xv[1];
        uint4 p;
        p.x = (unsigned)f2bf(xa.x * d) | ((unsigned)f2bf(xa.y * d) << 16);
        p.y = (unsigned)f2bf(xa.z * d) | ((unsigned)f2bf(xa.w * d) << 16);
        p.z = (unsigned)f2bf(xb.x * d) | ((unsigned)f2bf(xb.y * d) << 16);
        p.w = (unsigned)f2bf(xb.z * d) | ((unsigned)f2bf(xb.w * d) << 16);
        *reinterpret_cast<uint4*>(&xs1[i * 8]) = p;
    }
    if (i == 0) rp[n] = E;
}

// ---- B5: direct CSR scatter. One random 4B write per edge (same cost as
// the old bin pass) but NO packed round-trip and NO csr pass afterwards.
// Within-row order is arrival order -- same nondeterminism as the old
// atomic-cursor build; aggregation is a sum, so semantics unchanged.
__global__ __launch_bounds__(256) void scatter_kernel(const int* __restrict__ src,
                                                      const int* __restrict__ dst,
                                                      int* __restrict__ cursor,
                                                      int* __restrict__ col, int E) {
    int stride = gridDim.x * 256;
    for (int e = blockIdx.x * 256 + threadIdx.x; e < E; e += stride) {
        int d = __builtin_nontemporal_load(&dst[e]);
        int s = __builtin_nontemporal_load(&src[e]);
        int pos = atomicAdd(&cursor[d], 1);
        __builtin_nontemporal_store(s, &col[pos]);
    }
}

// Layer-1 aggregation FUSED with gemm1 (R4 form: 1 lane = 1 edge, bf16 xs1).
__global__ __launch_bounds__(256) void agg8g1_kernel(
        const unsigned short* __restrict__ xs, const int* __restrict__ row_ptr,
        const int* __restrict__ col, const float* __restrict__ dinv,
        const float* __restrict__ W1, const float* __restrict__ b1,
        unsigned short* __restrict__ xs2, int n) {
    int wave = threadIdx.x >> 6;            // 4 waves/block = 4 nodes/block
    int node = blockIdx.x * 4 + wave;
    if (node >= n) return;
    int lane = threadIdx.x & 63;
    float w[8];
    float bias = b1[lane];
#pragma unroll
    for (int k = 0; k < 8; ++k) w[k] = W1[k * 64 + lane];   // L2-broadcast
    int e0 = row_ptr[node], e1 = row_ptr[node + 1];
    float a[8] = {0.f, 0.f, 0.f, 0.f, 0.f, 0.f, 0.f, 0.f};
    uint4 sv = *reinterpret_cast<const uint4*>(&xs[node * 8]);   // uniform
    int base = e0;
    for (; base + 64 <= e1; base += 64) {   // deg > 64: ~3e-7 of rows
        int c = __builtin_nontemporal_load(&col[base + lane]);
        uint4 v = *reinterpret_cast<const uint4*>(&xs[c * 8]);
        acc_bf8(v, 1.f, a);
    }
    if (base < e1) {                        // single masked pass (<=64 edges)
        int e = base + lane;
        int c = __builtin_nontemporal_load(&col[min(e, e1 - 1)]);
        uint4 v = *reinterpret_cast<const uint4*>(&xs[c * 8]);
        acc_bf8(v, (e < e1) ? 1.f : 0.f, a);
    }
    acc_bf8(sv, (lane == 0) ? 1.f : 0.f, a);   // self-loop, counted once
    // octet reduce: a[k] summed over the 8 lanes of this octet
#pragma unroll
    for (int k = 0; k < 8; ++k) {
        a[k] += __shfl_xor(a[k], 1);
        a[k] += __shfl_xor(a[k], 2);
        a[k] += __shfl_xor(a[k], 4);
    }
    // cross-octet reduce on one value per lane (feature = lane&7)
    float v8 = a[lane & 7];
    v8 += __shfl_xor(v8, 8);
    v8 += __shfl_xor(v8, 16);
    v8 += __shfl_xor(v8, 32);
    float d = dinv[node];
    float acc = bias;
#pragma unroll
    for (int k = 0; k < 8; ++k) acc += (__shfl(v8, k) * d) * w[k];
    xs2[node * 64 + lane] = f2bf(d * fmaxf(acc, 0.0f));
}

// D=64 aggregation over a bf16 feature table (rows = 128 B).
// Single-shot whole-row issue. BF16OUT: z stored as bf16.
template <bool BF16OUT>
__global__ __launch_bounds__(256) void agg64bf_kernel(
        const unsigned short* __restrict__ xs, const int* __restrict__ row_ptr,
        const int* __restrict__ col, const float* __restrict__ dinv,
        float* __restrict__ z, int n) {
    int wave = threadIdx.x >> 6;            // 4 waves/block = 4 nodes/block
    int node = blockIdx.x * 4 + wave;
    if (node >= n) return;
    int lane = threadIdx.x & 63;
    int j = lane >> 3, l = lane & 7;
    int e0 = row_ptr[node], e1 = row_ptr[node + 1];
    float a[8] = {0.f, 0.f, 0.f, 0.f, 0.f, 0.f, 0.f, 0.f};
    // self-row load issued first: shares the col-load wait
    uint4 sv = *reinterpret_cast<const uint4*>(&xs[node * 64 + 8 * l]);
    int base = e0;
    // rare fallback: keep remaining <= 48 edges (Poisson(32): ~0.2% of rows)
    for (; e1 - base > 48; base += 32) {
        int s0 = __builtin_nontemporal_load(&col[base + j]);
        int s1 = __builtin_nontemporal_load(&col[base + 8 + j]);
        int s2 = __builtin_nontemporal_load(&col[base + 16 + j]);
        int s3 = __builtin_nontemporal_load(&col[base + 24 + j]);
        uint4 v0 = *reinterpret_cast<const uint4*>(&xs[s0 * 64 + 8 * l]);
        uint4 v1 = *reinterpret_cast<const uint4*>(&xs[s1 * 64 + 8 * l]);
        uint4 v2 = *reinterpret_cast<const uint4*>(&xs[s2 * 64 + 8 * l]);
        uint4 v3 = *reinterpret_cast<const uint4*>(&xs[s3 * 64 + 8 * l]);
        acc_bf8(v0, 1.f, a); acc_bf8(v1, 1.f, a);
        acc_bf8(v2, 1.f, a); acc_bf8(v3, 1.f, a);
    }
    int rem = e1 - base;   // wave-uniform, 0..48
    if (rem > 0) {
        int e1m1 = e1 - 1;
        bool g4 = rem > 32, g5 = rem > 40;   // wave-uniform guards
        int i0 = base + j,      i1 = base + 8 + j;
        int i2 = base + 16 + j, i3 = base + 24 + j;
        int i4 = base + 32 + j, i5 = base + 40 + j;
        // all col loads issued back-to-back (clamped -> always in-bounds)
        int c0 = __builtin_nontemporal_load(&col[min(i0, e1m1)]);
        int c1 = __builtin_nontemporal_load(&col[min(i1, e1m1)]);
        int c2 = __builtin_nontemporal_load(&col[min(i2, e1m1)]);
        int c3 = __builtin_nontemporal_load(&col[min(i3, e1m1)]);
        int c4 = 0, c5 = 0;
        if (g4) c4 = __builtin_nontemporal_load(&col[min(i4, e1m1)]);
        if (g5) c5 = __builtin_nontemporal_load(&col[min(i5, e1m1)]);
        // all gathers issued back-to-back (progressive counted vmcnt waits)
        uint4 v0 = *reinterpret_cast<const uint4*>(&xs[c0 * 64 + 8 * l]);
        uint4 v1 = *reinterpret_cast<const uint4*>(&xs[c1 * 64 + 8 * l]);
        uint4 v2 = *reinterpret_cast<const uint4*>(&xs[c2 * 64 + 8 * l]);
        uint4 v3 = *reinterpret_cast<const uint4*>(&xs[c3 * 64 + 8 * l]);
        uint4 v4, v5;
        if (g4) v4 = *reinterpret_cast<const uint4*>(&xs[c4 * 64 + 8 * l]);
        if (g5) v5 = *reinterpret_cast<const uint4*>(&xs[c5 * 64 + 8 * l]);
        acc_bf8(v0, (i0 < e1) ? 1.f : 0.f, a);
        acc_bf8(v1, (i1 < e1) ? 1.f : 0.f, a);
        acc_bf8(v2, (i2 < e1) ? 1.f : 0.f, a);
        acc_bf8(v3, (i3 < e1) ? 1.f : 0.f, a);
        if (g4) acc_bf8(v4, (i4 < e1) ? 1.f : 0.f, a);
        if (g5) acc_bf8(v5, (i5 < e1) ? 1.f : 0.f, a);
    }
    acc_bf8(sv, (j == 0) ? 1.f : 0.f, a);   // self-loop term, counted once
#pragma unroll
    for (int k = 0; k < 8; ++k) {
        a[k] += __shfl_xor(a[k], 8);
        a[k] += __shfl_xor(a[k], 16);
        a[k] += __shfl_xor(a[k], 32);
    }
    if (j == 0) {
        float d = dinv[node];
        if constexpr (BF16OUT) {
            unsigned short* zh = reinterpret_cast<unsigned short*>(z);
            uint4 p;
            p.x = (unsigned)f2bf(a[0] * d) | ((unsigned)f2bf(a[1] * d) << 16);
            p.y = (unsigned)f2bf(a[2] * d) | ((unsigned)f2bf(a[3] * d) << 16);
            p.z = (unsigned)f2bf(a[4] * d) | ((unsigned)f2bf(a[5] * d) << 16);
            p.w = (unsigned)f2bf(a[6] * d) | ((unsigned)f2bf(a[7] * d) << 16);
            *reinterpret_cast<uint4*>(&zh[node * 64 + 8 * l]) = p;
        } else {
            float4 r0 = {a[0] * d, a[1] * d, a[2] * d, a[3] * d};
            float4 r1 = {a[4] * d, a[5] * d, a[6] * d, a[7] * d};
            *reinterpret_cast<float4*>(&z[node * 64 + 8 * l]) = r0;
            *reinterpret_cast<float4*>(&z[node * 64 + 8 * l + 4]) = r1;
        }
    }
}

// Y[row, :] = opt_scale(dinv[row]) * opt_relu( X[row,:] @ W + opt_bias )
// Register-blocked 4x4, bounded unroll (R16 proven form).
// BF16IN: X is packed bf16 (expanded to fp32 during LDS staging).
// BF16OUT: store Y as packed bf16 (ushort) instead of fp32.
template <int K, int M, bool BIAS, bool RELU, bool SCALE, bool BF16IN, bool BF16OUT>
__global__ __launch_bounds__(256) void gemm_kernel(
        const float* __restrict__ X, const float* __restrict__ W,
        const float* __restrict__ b, const float* __restrict__ dinv,
        float* __restrict__ Y, int nrows) {
    constexpr int CG = M / 4;          // col-groups (gemm2: 32, gemm3: 16)
    constexpr int RG = 256 / CG;       // row-groups  (gemm2: 8,  gemm3: 16)
    constexpr int ROWS = RG * 4;       // rows/tile   (gemm2: 32, gemm3: 64)
    constexpr int XSTR = K + 4;        // padded X stride (bank decorrelation)
    __shared__ float Wl[K * M];        // 32 KB
    __shared__ float Xl[ROWS * XSTR];
    __shared__ float Bl[M];
    int tid = threadIdx.x;
    {   // float4 weight staging
        const float4* Wv = reinterpret_cast<const float4*>(W);
        float4* Wlv = reinterpret_cast<float4*>(Wl);
        for (int i = tid; i < K * M / 4; i += 256) Wlv[i] = Wv[i];
    }
    if (tid < M) Bl[tid] = BIAS ? b[tid] : 0.0f;
    int cg = tid % CG;
    int rg = tid / CG;
    int ntiles = (nrows + ROWS - 1) / ROWS;
    for (int tile = blockIdx.x; tile < ntiles; tile += gridDim.x) {
        int row0 = tile * ROWS;
        __syncthreads();
        {   // stage X tile (4 elems/iter, padded rows, zero-fill tail)
            int base4 = row0 * (K / 4);
            int tot4 = nrows * (K / 4);
            for (int i = tid; i < ROWS * K / 4; i += 256) {
                float4 v = {0.f, 0.f, 0.f, 0.f};
                if (base4 + i < tot4) {
                    if constexpr (BF16IN) {
                        uint2 raw = reinterpret_cast<const uint2*>(X)[base4 + i];
                        v.x = __uint_as_float(raw.x << 16);
                        v.y = __uint_as_float(raw.x & 0xffff0000u);
                        v.z = __uint_as_float(raw.y << 16);
                        v.w = __uint_as_float(raw.y & 0xffff0000u);
                    } else {
                        v = reinterpret_cast<const float4*>(X)[base4 + i];
                    }
                }
                int rr = i / (K / 4), kk = i % (K / 4);
                *reinterpret_cast<float4*>(&Xl[rr * XSTR + kk * 4]) = v;
            }
        }
        __syncthreads();
        float4 acc[4];
#pragma unroll
        for (int rr = 0; rr < 4; ++rr)
            acc[rr] = *reinterpret_cast<const float4*>(&Bl[cg * 4]);
#pragma unroll 1
        for (int k = 0; k < K; k += 4) {
            const float4 w0 = *reinterpret_cast<const float4*>(&Wl[(k + 0) * M + cg * 4]);
            const float4 w1 = *reinterpret_cast<const float4*>(&Wl[(k + 1) * M + cg * 4]);
            const float4 w2 = *reinterpret_cast<const float4*>(&Wl[(k + 2) * M + cg * 4]);
            const float4 w3 = *reinterpret_cast<const float4*>(&Wl[(k + 3) * M + cg * 4]);
#pragma unroll
            for (int rr = 0; rr < 4; ++rr) {
                const float4 xv = *reinterpret_cast<const float4*>(
                    &Xl[(rg * 4 + rr) * XSTR + k]);
                acc[rr].x += xv.x * w0.x + xv.y * w1.x + xv.z * w2.x + xv.w * w3.x;
                acc[rr].y += xv.x * w0.y + xv.y * w1.y + xv.z * w2.y + xv.w * w3.y;
                acc[rr].z += xv.x * w0.z + xv.y * w1.z + xv.z * w2.z + xv.w * w3.z;
                acc[rr].w += xv.x * w0.w + xv.y * w1.w + xv.z * w2.w + xv.w * w3.w;
            }
        }
#pragma unroll
        for (int rr = 0; rr < 4; ++rr) {
            int row = row0 + rg * 4 + rr;
            if (row < nrows) {
                float4 a = acc[rr];
                if constexpr (RELU) {
                    a.x = fmaxf(a.x, 0.f); a.y = fmaxf(a.y, 0.f);
                    a.z = fmaxf(a.z, 0.f); a.w = fmaxf(a.w, 0.f);
                }
                if constexpr (SCALE) {
                    float d = dinv[row];
                    a.x *= d; a.y *= d; a.z *= d; a.w *= d;
                }
                if constexpr (BF16OUT) {
                    unsigned short* Yh = reinterpret_cast<unsigned short*>(Y);
                    uint2 p;
                    p.x = (unsigned)f2bf(a.x) | ((unsigned)f2bf(a.y) << 16);
                    p.y = (unsigned)f2bf(a.z) | ((unsigned)f2bf(a.w) << 16);
                    *reinterpret_cast<uint2*>(&Yh[row * M + cg * 4]) = p;
                } else {
                    *reinterpret_cast<float4*>(&Y[row * M + cg * 4]) = a;
                }
            }
        }
    }
}

// h3 = relu(z3 + b3); pool sums/counts per graph (R18 proven form).
#define POOL_NPB 128   // nodes per block (32 per wave, contiguous)
__global__ __launch_bounds__(256) void pool_kernel(
        const float* __restrict__ z3, const float* __restrict__ b3,
        const int* __restrict__ batch, float* __restrict__ sums,
        float* __restrict__ cntf, int n) {
    int wave = threadIdx.x >> 6;
    int lane = threadIdx.x & 63;   // feature index
    int node0 = blockIdx.x * POOL_NPB + wave * 32;
    int nodeEnd = min(node0 + 32, n);
    if (node0 >= n) return;
    float bias = b3[lane];
    float acc = 0.0f, cnt = 0.0f;
    int curg = -1;
    for (int node = node0; node < nodeEnd; ++node) {
        int g = batch[node];               // wave-uniform (lane = feature)
        if (g != curg) {                   // wave-uniform branch
            if (curg >= 0) {
                atomicAdd(&sums[curg * 64 + lane], acc);
                if (lane == 0) atomicAdd(&cntf[curg], cnt);
            }
            curg = g; acc = 0.0f; cnt = 0.0f;
        }
        acc += fmaxf(__builtin_nontemporal_load(&z3[node * 64 + lane]) + bias, 0.0f);
        cnt += 1.0f;
    }
    if (curg >= 0) {
        atomicAdd(&sums[curg * 64 + lane], acc);
        if (lane == 0) atomicAdd(&cntf[curg], cnt);
    }
}

// per-graph: g = sums/max(cnt,1); hid = relu(g@Wl1+bl1); out = hid@Wl2+bl2
__global__ void mlp_kernel(const float* __restrict__ sums, const float* __restrict__ cntf,
                           const float* __restrict__ Wl1, const float* __restrict__ bl1,
                           const float* __restrict__ Wl2, const float* __restrict__ bl2,
                           float* __restrict__ out) {
    __shared__ float gv[64];
    __shared__ float hid[32];
    int g = blockIdx.x, t = threadIdx.x;
    float denom = fmaxf(cntf[g], 1.0f);
    gv[t] = sums[g * 64 + t] / denom;
    __syncthreads();
    if (t < 32) {
        float a = bl1[t];
#pragma unroll
        for (int k = 0; k < 64; ++k) a += gv[k] * Wl1[k * 32 + t];
        hid[t] = fmaxf(a, 0.0f);
    }
    __syncthreads();
    if (t == 0) {
        float o = bl2[0];
#pragma unroll
        for (int k = 0; k < 32; ++k) o += hid[k] * Wl2[k];
        out[g] = o;
    }
}

extern "C" void kernel_launch(void* const* d_in, const int* in_sizes, int n_in,
                              void* d_out, int out_size, void* d_ws, size_t ws_size,
                              hipStream_t stream) {
    const float* x   = (const float*)d_in[0];
    const int* ei    = (const int*)d_in[1];
    const int* batch = (const int*)d_in[2];
    const float* W1  = (const float*)d_in[3];
    const float* b1  = (const float*)d_in[4];
    const float* W2  = (const float*)d_in[5];
    const float* b2  = (const float*)d_in[6];
    const float* W3  = (const float*)d_in[7];
    const float* b3  = (const float*)d_in[8];
    const float* Wl1 = (const float*)d_in[9];
    const float* bl1 = (const float*)d_in[10];
    const float* Wl2 = (const float*)d_in[11];
    const float* bl2 = (const float*)d_in[12];
    float* out = (float*)d_out;

    const int N = N_NODES;
    const int E = in_sizes[1] / 2;   // 3.2M
    const int* src = ei;
    const int* dst = ei + E;

    char* ws = (char*)d_ws;
    float* sums    = (float*)(ws + OFF_SUMS);
    float* cntf    = (float*)(ws + OFF_CNTF);
    int*   deg     = (int*)(ws + OFF_DEG);
    int*   bsum2   = (int*)(ws + OFF_BSUM2);
    int*   row_ptr = (int*)(ws + OFF_ROWPTR);
    int*   cursor  = (int*)(ws + OFF_CURS);
    float* dinv    = (float*)(ws + OFF_DINV);
    int*   col     = (int*)(ws + OFF_COL);
    unsigned short* xs1 = (unsigned short*)(ws + OFF_XS1);   // bf16
    float* bufQ    = (float*)(ws + OFF_BUFQ);   // bf16 xs2, later fp32 z3
    float* bufR    = (float*)(ws + OFF_BUFR);   // bf16 z2, later bf16 ys
    float* bufP    = (float*)(ws + OFF_BUFP);   // bf16 h2

    // CSR build (node-granular, single scatter):
    // zero -> deg -> scan1 -> scan2 -> fin(row_ptr/cursor/dinv/xs1) -> scatter
    zero_kernel<<<456, 256, 0, stream>>>((int*)ws);
    deg_kernel<<<1024, 256, 0, stream>>>(dst, deg, E);
    scan1_kernel<<<SCAN1_BLKS, 1024, 0, stream>>>(deg, row_ptr, bsum2, N);
    scan2_kernel<<<1, 128, 0, stream>>>(bsum2);
    fin_kernel<<<SCAN1_BLKS, 1024, 0, stream>>>(bsum2, deg, x, row_ptr, cursor,
                                                dinv, xs1, N, E);
    scatter_kernel<<<1024, 256, 0, stream>>>(src, dst, cursor, col, E);

    // Layer 1 (agg + gemm1 fused): xs2(bf16) = dinv*relu((agg xs1)@W1+b1)
    agg8g1_kernel<<<(N + 3) / 4, 256, 0, stream>>>(xs1, row_ptr, col, dinv, W1, b1,
                                                   (unsigned short*)bufQ, N);

    // Layer 2: z2(bf16) = agg_bf16(xs2) ; h2(bf16) = relu(z2@W2+b2)
    agg64bf_kernel<true><<<(N + 3) / 4, 256, 0, stream>>>(
        (const unsigned short*)bufQ, row_ptr, col, dinv, bufR, N);
    gemm_kernel<64, 128, true, true, false, true, true><<<3125, 256, 0, stream>>>(
        bufR, W2, b2, nullptr, bufP, N);

    // Layer 3: ys(bf16) = dinv*(h2@W3) ; z3(fp32) = agg_bf16(ys)
    gemm_kernel<128, 64, false, false, true, true, true><<<1563, 256, 0, stream>>>(
        bufP, W3, nullptr, dinv, bufR, N);
    agg64bf_kernel<false><<<(N + 3) / 4, 256, 0, stream>>>(
        (const unsigned short*)bufR, row_ptr, col, dinv, bufQ, N);

    // Pool + MLP head
    pool_kernel<<<(N + POOL_NPB - 1) / POOL_NPB, 256, 0, stream>>>(bufQ, b3, batch, sums, cntf, N);
    mlp_kernel<<<N_GRAPHS, 64, 0, stream>>>(sums, cntf, Wl1, bl1, Wl2, bl2, out);
}

// Round 6
// 430.610 us; speedup vs baseline: 1.6913x; 1.6913x over previous
//
#include <hip/hip_runtime.h>
#include <hip/hip_bf16.h>

#define N_NODES 100000
#define N_EDGES 3200000
#define N_GRAPHS 256
#define NB_BUCKETS 196      // ceil(100000 / 512)
#define BSHIFT 9            // 512 nodes per bucket
#define NBLK 256            // blocks for hist/bin passes
#define SCAN_BLKS 49        // 50176 / 1024
#define CSR_CAP 22528       // LDS staging capacity (88 KB); avg bucket 16.4K edges

// ---------------- workspace layout (bytes) ----------------
#define OFF_SUMS      0u            // float[256*64] pool sums (zeroed in hist)
#define OFF_CNTF      65536u        // float[256] pool counts (zeroed in hist)
#define ZERO_BYTES    66560u
#define OFF_HIST      66560u        // int[196*256] (bucket-major) per-(bucket,block) counts
#define OFF_BSUM      267264u       // int[64] scan block sums
#define OFF_ROWPTR    267776u       // int[N+1]
#define OFF_DINV      668160u       // float[N]
#define OFF_COL       1068544u     // int[E]
#define OFF_XS1       13868544u     // bf16[N*8]
#define OFF_BUFQ      20268544u     // bf16 xs2 [N*64], later fp32 z3 [N*64]
#define OFF_BUFR      45868544u     // bf16 z2 [N*64], later bf16 ys [N*64]
#define OFF_BUFP      71468544u     // bf16 h2 [N*128]; ALIASED: packed[E] (dead before h2)
#define OFF_PAIRS     OFF_BUFP
// total ~97 MB

// round-to-nearest-even float -> bf16 (values are finite; no NaN guard needed)
__device__ __forceinline__ unsigned short f2bf(float f) {
    unsigned u = __float_as_uint(f);
    return (unsigned short)((u + 0x7fffu + ((u >> 16) & 1u)) >> 16);
}

// unpack uint4 (8 bf16) and accumulate m * value into a[0..7] (fp32)
__device__ __forceinline__ void acc_bf8(uint4 v, float m, float* a) {
    a[0] += m * __uint_as_float(v.x << 16);
    a[1] += m * __uint_as_float(v.x & 0xffff0000u);
    a[2] += m * __uint_as_float(v.y << 16);
    a[3] += m * __uint_as_float(v.y & 0xffff0000u);
    a[4] += m * __uint_as_float(v.z << 16);
    a[5] += m * __uint_as_float(v.z & 0xffff0000u);
    a[6] += m * __uint_as_float(v.w << 16);
    a[7] += m * __uint_as_float(v.w & 0xffff0000u);
}

// ---- P1: per-(bucket,block) histogram of dst. Also zeroes the pool
// accumulators.
__global__ __launch_bounds__(256) void hist_kernel(const int* __restrict__ dst,
                                                   int* __restrict__ hist,
                                                   int* __restrict__ zbase,
                                                   int E, int epb) {
    __shared__ int h[NB_BUCKETS];
    int t = threadIdx.x, blk = blockIdx.x;
    int gid = blk * 256 + t;
    if (gid < (int)(ZERO_BYTES / 4)) zbase[gid] = 0;
    if (t < NB_BUCKETS) h[t] = 0;
    __syncthreads();
    int e0 = blk * epb, e1 = min(e0 + epb, E);
    for (int e = e0 + t; e < e1; e += 256)
        atomicAdd(&h[__builtin_nontemporal_load(&dst[e]) >> BSHIFT], 1);
    __syncthreads();
    if (t < NB_BUCKETS) hist[t * NBLK + blk] = h[t];
}

// ---- P2: block-local exclusive scan of hist[50176] + per-block sums.
__global__ __launch_bounds__(1024) void scanhA_kernel(int* __restrict__ hist,
                                                      int* __restrict__ bsum) {
    __shared__ int s[1024];
    int t = threadIdx.x;
    int i = blockIdx.x * 1024 + t;     // 49*1024 == 50176 exactly
    int v = hist[i];
    s[t] = v;
    __syncthreads();
    for (int off = 1; off < 1024; off <<= 1) {
        int add = (t >= off) ? s[t - off] : 0;
        __syncthreads();
        s[t] += add;
        __syncthreads();
    }
    hist[i] = s[t] - v;                // block-local exclusive
    if (t == 1023) bsum[blockIdx.x] = s[t];
}

// ---- P3: bin edges, PACKED (dl<<17 | src), local offset scan.
// (R2 proven direct-scatter form with LDS cursors.)
__global__ __launch_bounds__(256) void bin_kernel(const int* __restrict__ src,
                                                  const int* __restrict__ dst,
                                                  const int* __restrict__ hist,
                                                  const int* __restrict__ bsum,
                                                  int* __restrict__ packed, int E, int epb) {
    __shared__ int cur[NB_BUCKETS];
    __shared__ int boffL[SCAN_BLKS];
    int t = threadIdx.x, blk = blockIdx.x;
    if (t < 64) {
        int orig = (t < SCAN_BLKS) ? bsum[t] : 0;
        int v = orig;
        for (int off = 1; off < 64; off <<= 1) {
            int up = __shfl_up(v, off);
            if (t >= off) v += up;
        }
        if (t < SCAN_BLKS) boffL[t] = v - orig;   // exclusive
    }
    __syncthreads();
    if (t < NB_BUCKETS) {
        int i = t * NBLK + blk;
        cur[t] = hist[i] + boffL[i >> 10];
    }
    __syncthreads();
    int e0 = blk * epb, e1 = min(e0 + epb, E);
    for (int e = e0 + t; e < e1; e += 256) {
        int d = __builtin_nontemporal_load(&dst[e]);
        int sv = __builtin_nontemporal_load(&src[e]);
        int pos = atomicAdd(&cur[d >> BSHIFT], 1);
        packed[pos] = ((d & 511) << 17) | sv;
    }
}

// ---- P4: per-bucket CSR finalize + xs1 = bf16(dinv*x).
__global__ __launch_bounds__(512) void csr_kernel(const int* __restrict__ packed,
                                                  const int* __restrict__ hist,
                                                  const int* __restrict__ bsum,
                                                  const float* __restrict__ x,
                                                  int* __restrict__ row_ptr,
                                                  float* __restrict__ dinv,
                                                  unsigned short* __restrict__ xs1,
                                                  int* __restrict__ col, int E) {
    __shared__ int cntL[512];
    __shared__ int rsL[512];
    __shared__ int fillL[512];
    __shared__ int boffL[SCAN_BLKS];
    __shared__ int srcL[CSR_CAP];   // 88 KB staging
    int t = threadIdx.x, b = blockIdx.x;
    int lo = b << BSHIFT;
    int nloc = min(512, N_NODES - lo);
    cntL[t] = 0;
    fillL[t] = 0;
    if (t < 64) {
        int orig = (t < SCAN_BLKS) ? bsum[t] : 0;
        int v = orig;
        for (int off = 1; off < 64; off <<= 1) {
            int up = __shfl_up(v, off);
            if (t >= off) v += up;
        }
        if (t < SCAN_BLKS) boffL[t] = v - orig;   // exclusive
    }
    __syncthreads();
    int i0 = b * NBLK;
    int start = hist[i0] + boffL[i0 >> 10];
    int end;
    if (b == NB_BUCKETS - 1) end = E;
    else {
        int i1 = (b + 1) * NBLK;
        end = hist[i1] + boffL[i1 >> 10];
    }
    for (int e = start + t; e < end; e += 512)
        atomicAdd(&cntL[packed[e] >> 17], 1);
    __syncthreads();
    int v = cntL[t];
    __syncthreads();
    for (int off = 1; off < 512; off <<= 1) {     // inclusive scan (Hillis-Steele)
        int add = (t >= off) ? cntL[t - off] : 0;
        __syncthreads();
        cntL[t] += add;
        __syncthreads();
    }
    int rowstart = start + cntL[t] - v;           // exclusive + bucket base
    rsL[t] = rowstart;
    if (t < nloc) {
        int node = lo + t;
        row_ptr[node] = rowstart;
        float d = rsqrtf((float)(v + 1));
        dinv[node] = d;
        const float4* xv = reinterpret_cast<const float4*>(x) + node * 2;
        float4 xa = xv[0], xb = xv[1];
        uint4 p;
        p.x = (unsigned)f2bf(xa.x * d) | ((unsigned)f2bf(xa.y * d) << 16);
        p.y = (unsigned)f2bf(xa.z * d) | ((unsigned)f2bf(xa.w * d) << 16);
        p.z = (unsigned)f2bf(xb.x * d) | ((unsigned)f2bf(xb.y * d) << 16);
        p.w = (unsigned)f2bf(xb.z * d) | ((unsigned)f2bf(xb.w * d) << 16);
        *reinterpret_cast<uint4*>(&xs1[node * 8]) = p;
    }
    if (b == NB_BUCKETS - 1 && t == 0) row_ptr[N_NODES] = E;
    __syncthreads();
    for (int e = start + t; e < end; e += 512) {
        int p = packed[e];
        int dl = p >> 17;
        int pos = rsL[dl] + atomicAdd(&fillL[dl], 1);
        int rel = pos - start;
        if (rel < CSR_CAP) srcL[rel] = p & 0x1FFFF;
        else col[pos] = p & 0x1FFFF;          // overflow fallback
    }
    __syncthreads();
    int lim = min(end - start, CSR_CAP);
    for (int i = t; i < lim; i += 512)
        col[start + i] = srcL[i];             // coalesced write-out
}

// Layer-1 aggregation FUSED with gemm1 (R4 form: 1 lane = 1 edge, bf16 xs1).
__global__ __launch_bounds__(256) void agg8g1_kernel(
        const unsigned short* __restrict__ xs, const int* __restrict__ row_ptr,
        const int* __restrict__ col, const float* __restrict__ dinv,
        const float* __restrict__ W1, const float* __restrict__ b1,
        unsigned short* __restrict__ xs2, int n) {
    int wave = threadIdx.x >> 6;            // 4 waves/block = 4 nodes/block
    int node = blockIdx.x * 4 + wave;
    if (node >= n) return;
    int lane = threadIdx.x & 63;
    float w[8];
    float bias = b1[lane];
#pragma unroll
    for (int k = 0; k < 8; ++k) w[k] = W1[k * 64 + lane];   // L2-broadcast
    int e0 = row_ptr[node], e1 = row_ptr[node + 1];
    float a[8] = {0.f, 0.f, 0.f, 0.f, 0.f, 0.f, 0.f, 0.f};
    uint4 sv = *reinterpret_cast<const uint4*>(&xs[node * 8]);   // uniform
    int base = e0;
    for (; base + 64 <= e1; base += 64) {   // deg > 64: ~3e-7 of rows
        int c = __builtin_nontemporal_load(&col[base + lane]);
        uint4 v = *reinterpret_cast<const uint4*>(&xs[c * 8]);
        acc_bf8(v, 1.f, a);
    }
    if (base < e1) {                        // single masked pass (<=64 edges)
        int e = base + lane;
        int c = __builtin_nontemporal_load(&col[min(e, e1 - 1)]);
        uint4 v = *reinterpret_cast<const uint4*>(&xs[c * 8]);
        acc_bf8(v, (e < e1) ? 1.f : 0.f, a);
    }
    acc_bf8(sv, (lane == 0) ? 1.f : 0.f, a);   // self-loop, counted once
    // octet reduce: a[k] summed over the 8 lanes of this octet
#pragma unroll
    for (int k = 0; k < 8; ++k) {
        a[k] += __shfl_xor(a[k], 1);
        a[k] += __shfl_xor(a[k], 2);
        a[k] += __shfl_xor(a[k], 4);
    }
    // cross-octet reduce on one value per lane (feature = lane&7)
    float v8 = a[lane & 7];
    v8 += __shfl_xor(v8, 8);
    v8 += __shfl_xor(v8, 16);
    v8 += __shfl_xor(v8, 32);
    float d = dinv[node];
    float acc = bias;
#pragma unroll
    for (int k = 0; k < 8; ++k) acc += (__shfl(v8, k) * d) * w[k];
    xs2[node * 64 + lane] = f2bf(d * fmaxf(acc, 0.0f));
}

// D=64 aggregation over a bf16 feature table (rows = 128 B).
// Single-shot whole-row issue. BF16OUT: z stored as bf16.
// Node-range [n0, n1): split into quarter-dispatches this round so the
// top-5 profile exposes the mid-tier kernels (diagnostic instrumentation).
template <bool BF16OUT>
__global__ __launch_bounds__(256) void agg64bf_kernel(
        const unsigned short* __restrict__ xs, const int* __restrict__ row_ptr,
        const int* __restrict__ col, const float* __restrict__ dinv,
        float* __restrict__ z, int n0, int n1) {
    int wave = threadIdx.x >> 6;            // 4 waves/block = 4 nodes/block
    int node = n0 + blockIdx.x * 4 + wave;
    if (node >= n1) return;
    int lane = threadIdx.x & 63;
    int j = lane >> 3, l = lane & 7;
    int e0 = row_ptr[node], e1 = row_ptr[node + 1];
    float a[8] = {0.f, 0.f, 0.f, 0.f, 0.f, 0.f, 0.f, 0.f};
    // self-row load issued first: shares the col-load wait
    uint4 sv = *reinterpret_cast<const uint4*>(&xs[node * 64 + 8 * l]);
    int base = e0;
    // rare fallback: keep remaining <= 48 edges (Poisson(32): ~0.2% of rows)
    for (; e1 - base > 48; base += 32) {
        int s0 = __builtin_nontemporal_load(&col[base + j]);
        int s1 = __builtin_nontemporal_load(&col[base + 8 + j]);
        int s2 = __builtin_nontemporal_load(&col[base + 16 + j]);
        int s3 = __builtin_nontemporal_load(&col[base + 24 + j]);
        uint4 v0 = *reinterpret_cast<const uint4*>(&xs[s0 * 64 + 8 * l]);
        uint4 v1 = *reinterpret_cast<const uint4*>(&xs[s1 * 64 + 8 * l]);
        uint4 v2 = *reinterpret_cast<const uint4*>(&xs[s2 * 64 + 8 * l]);
        uint4 v3 = *reinterpret_cast<const uint4*>(&xs[s3 * 64 + 8 * l]);
        acc_bf8(v0, 1.f, a); acc_bf8(v1, 1.f, a);
        acc_bf8(v2, 1.f, a); acc_bf8(v3, 1.f, a);
    }
    int rem = e1 - base;   // wave-uniform, 0..48
    if (rem > 0) {
        int e1m1 = e1 - 1;
        bool g4 = rem > 32, g5 = rem > 40;   // wave-uniform guards
        int i0 = base + j,      i1 = base + 8 + j;
        int i2 = base + 16 + j, i3 = base + 24 + j;
        int i4 = base + 32 + j, i5 = base + 40 + j;
        // all col loads issued back-to-back (clamped -> always in-bounds)
        int c0 = __builtin_nontemporal_load(&col[min(i0, e1m1)]);
        int c1 = __builtin_nontemporal_load(&col[min(i1, e1m1)]);
        int c2 = __builtin_nontemporal_load(&col[min(i2, e1m1)]);
        int c3 = __builtin_nontemporal_load(&col[min(i3, e1m1)]);
        int c4 = 0, c5 = 0;
        if (g4) c4 = __builtin_nontemporal_load(&col[min(i4, e1m1)]);
        if (g5) c5 = __builtin_nontemporal_load(&col[min(i5, e1m1)]);
        // all gathers issued back-to-back (progressive counted vmcnt waits)
        uint4 v0 = *reinterpret_cast<const uint4*>(&xs[c0 * 64 + 8 * l]);
        uint4 v1 = *reinterpret_cast<const uint4*>(&xs[c1 * 64 + 8 * l]);
        uint4 v2 = *reinterpret_cast<const uint4*>(&xs[c2 * 64 + 8 * l]);
        uint4 v3 = *reinterpret_cast<const uint4*>(&xs[c3 * 64 + 8 * l]);
        uint4 v4, v5;
        if (g4) v4 = *reinterpret_cast<const uint4*>(&xs[c4 * 64 + 8 * l]);
        if (g5) v5 = *reinterpret_cast<const uint4*>(&xs[c5 * 64 + 8 * l]);
        acc_bf8(v0, (i0 < e1) ? 1.f : 0.f, a);
        acc_bf8(v1, (i1 < e1) ? 1.f : 0.f, a);
        acc_bf8(v2, (i2 < e1) ? 1.f : 0.f, a);
        acc_bf8(v3, (i3 < e1) ? 1.f : 0.f, a);
        if (g4) acc_bf8(v4, (i4 < e1) ? 1.f : 0.f, a);
        if (g5) acc_bf8(v5, (i5 < e1) ? 1.f : 0.f, a);
    }
    acc_bf8(sv, (j == 0) ? 1.f : 0.f, a);   // self-loop term, counted once
#pragma unroll
    for (int k = 0; k < 8; ++k) {
        a[k] += __shfl_xor(a[k], 8);
        a[k] += __shfl_xor(a[k], 16);
        a[k] += __shfl_xor(a[k], 32);
    }
    if (j == 0) {
        float d = dinv[node];
        if constexpr (BF16OUT) {
            unsigned short* zh = reinterpret_cast<unsigned short*>(z);
            uint4 p;
            p.x = (unsigned)f2bf(a[0] * d) | ((unsigned)f2bf(a[1] * d) << 16);
            p.y = (unsigned)f2bf(a[2] * d) | ((unsigned)f2bf(a[3] * d) << 16);
            p.z = (unsigned)f2bf(a[4] * d) | ((unsigned)f2bf(a[5] * d) << 16);
            p.w = (unsigned)f2bf(a[6] * d) | ((unsigned)f2bf(a[7] * d) << 16);
            *reinterpret_cast<uint4*>(&zh[node * 64 + 8 * l]) = p;
        } else {
            float4 r0 = {a[0] * d, a[1] * d, a[2] * d, a[3] * d};
            float4 r1 = {a[4] * d, a[5] * d, a[6] * d, a[7] * d};
            *reinterpret_cast<float4*>(&z[node * 64 + 8 * l]) = r0;
            *reinterpret_cast<float4*>(&z[node * 64 + 8 * l + 4]) = r1;
        }
    }
}

// Y[row, :] = opt_scale(dinv[row]) * opt_relu( X[row,:] @ W + opt_bias )
// Register-blocked 4x4, bounded unroll (R16 proven form).
// BF16IN: X is packed bf16 (expanded to fp32 during LDS staging).
// BF16OUT: store Y as packed bf16 (ushort) instead of fp32.
template <int K, int M, bool BIAS, bool RELU, bool SCALE, bool BF16IN, bool BF16OUT>
__global__ __launch_bounds__(256) void gemm_kernel(
        const float* __restrict__ X, const float* __restrict__ W,
        const float* __restrict__ b, const float* __restrict__ dinv,
        float* __restrict__ Y, int nrows) {
    constexpr int CG = M / 4;          // col-groups (gemm2: 32, gemm3: 16)
    constexpr int RG = 256 / CG;       // row-groups  (gemm2: 8,  gemm3: 16)
    constexpr int ROWS = RG * 4;       // rows/tile   (gemm2: 32, gemm3: 64)
    constexpr int XSTR = K + 4;        // padded X stride (bank decorrelation)
    __shared__ float Wl[K * M];        // 32 KB
    __shared__ float Xl[ROWS * XSTR];
    __shared__ float Bl[M];
    int tid = threadIdx.x;
    {   // float4 weight staging
        const float4* Wv = reinterpret_cast<const float4*>(W);
        float4* Wlv = reinterpret_cast<float4*>(Wl);
        for (int i = tid; i < K * M / 4; i += 256) Wlv[i] = Wv[i];
    }
    if (tid < M) Bl[tid] = BIAS ? b[tid] : 0.0f;
    int cg = tid % CG;
    int rg = tid / CG;
    int ntiles = (nrows + ROWS - 1) / ROWS;
    for (int tile = blockIdx.x; tile < ntiles; tile += gridDim.x) {
        int row0 = tile * ROWS;
        __syncthreads();
        {   // stage X tile (4 elems/iter, padded rows, zero-fill tail)
            int base4 = row0 * (K / 4);
            int tot4 = nrows * (K / 4);
            for (int i = tid; i < ROWS * K / 4; i += 256) {
                float4 v = {0.f, 0.f, 0.f, 0.f};
                if (base4 + i < tot4) {
                    if constexpr (BF16IN) {
                        uint2 raw = reinterpret_cast<const uint2*>(X)[base4 + i];
                        v.x = __uint_as_float(raw.x << 16);
                        v.y = __uint_as_float(raw.x & 0xffff0000u);
                        v.z = __uint_as_float(raw.y << 16);
                        v.w = __uint_as_float(raw.y & 0xffff0000u);
                    } else {
                        v = reinterpret_cast<const float4*>(X)[base4 + i];
                    }
                }
                int rr = i / (K / 4), kk = i % (K / 4);
                *reinterpret_cast<float4*>(&Xl[rr * XSTR + kk * 4]) = v;
            }
        }
        __syncthreads();
        float4 acc[4];
#pragma unroll
        for (int rr = 0; rr < 4; ++rr)
            acc[rr] = *reinterpret_cast<const float4*>(&Bl[cg * 4]);
#pragma unroll 1
        for (int k = 0; k < K; k += 4) {
            const float4 w0 = *reinterpret_cast<const float4*>(&Wl[(k + 0) * M + cg * 4]);
            const float4 w1 = *reinterpret_cast<const float4*>(&Wl[(k + 1) * M + cg * 4]);
            const float4 w2 = *reinterpret_cast<const float4*>(&Wl[(k + 2) * M + cg * 4]);
            const float4 w3 = *reinterpret_cast<const float4*>(&Wl[(k + 3) * M + cg * 4]);
#pragma unroll
            for (int rr = 0; rr < 4; ++rr) {
                const float4 xv = *reinterpret_cast<const float4*>(
                    &Xl[(rg * 4 + rr) * XSTR + k]);
                acc[rr].x += xv.x * w0.x + xv.y * w1.x + xv.z * w2.x + xv.w * w3.x;
                acc[rr].y += xv.x * w0.y + xv.y * w1.y + xv.z * w2.y + xv.w * w3.y;
                acc[rr].z += xv.x * w0.z + xv.y * w1.z + xv.z * w2.z + xv.w * w3.z;
                acc[rr].w += xv.x * w0.w + xv.y * w1.w + xv.z * w2.w + xv.w * w3.w;
            }
        }
#pragma unroll
        for (int rr = 0; rr < 4; ++rr) {
            int row = row0 + rg * 4 + rr;
            if (row < nrows) {
                float4 a = acc[rr];
                if constexpr (RELU) {
                    a.x = fmaxf(a.x, 0.f); a.y = fmaxf(a.y, 0.f);
                    a.z = fmaxf(a.z, 0.f); a.w = fmaxf(a.w, 0.f);
                }
                if constexpr (SCALE) {
                    float d = dinv[row];
                    a.x *= d; a.y *= d; a.z *= d; a.w *= d;
                }
                if constexpr (BF16OUT) {
                    unsigned short* Yh = reinterpret_cast<unsigned short*>(Y);
                    uint2 p;
                    p.x = (unsigned)f2bf(a.x) | ((unsigned)f2bf(a.y) << 16);
                    p.y = (unsigned)f2bf(a.z) | ((unsigned)f2bf(a.w) << 16);
                    *reinterpret_cast<uint2*>(&Yh[row * M + cg * 4]) = p;
                } else {
                    *reinterpret_cast<float4*>(&Y[row * M + cg * 4]) = a;
                }
            }
        }
    }
}

// h3 = relu(z3 + b3); pool sums/counts per graph (R18 proven form).
#define POOL_NPB 128   // nodes per block (32 per wave, contiguous)
__global__ __launch_bounds__(256) void pool_kernel(
        const float* __restrict__ z3, const float* __restrict__ b3,
        const int* __restrict__ batch, float* __restrict__ sums,
        float* __restrict__ cntf, int n) {
    int wave = threadIdx.x >> 6;
    int lane = threadIdx.x & 63;   // feature index
    int node0 = blockIdx.x * POOL_NPB + wave * 32;
    int nodeEnd = min(node0 + 32, n);
    if (node0 >= n) return;
    float bias = b3[lane];
    float acc = 0.0f, cnt = 0.0f;
    int curg = -1;
    for (int node = node0; node < nodeEnd; ++node) {
        int g = batch[node];               // wave-uniform (lane = feature)
        if (g != curg) {                   // wave-uniform branch
            if (curg >= 0) {
                atomicAdd(&sums[curg * 64 + lane], acc);
                if (lane == 0) atomicAdd(&cntf[curg], cnt);
            }
            curg = g; acc = 0.0f; cnt = 0.0f;
        }
        acc += fmaxf(__builtin_nontemporal_load(&z3[node * 64 + lane]) + bias, 0.0f);
        cnt += 1.0f;
    }
    if (curg >= 0) {
        atomicAdd(&sums[curg * 64 + lane], acc);
        if (lane == 0) atomicAdd(&cntf[curg], cnt);
    }
}

// per-graph: g = sums/max(cnt,1); hid = relu(g@Wl1+bl1); out = hid@Wl2+bl2
__global__ void mlp_kernel(const float* __restrict__ sums, const float* __restrict__ cntf,
                           const float* __restrict__ Wl1, const float* __restrict__ bl1,
                           const float* __restrict__ Wl2, const float* __restrict__ bl2,
                           float* __restrict__ out) {
    __shared__ float gv[64];
    __shared__ float hid[32];
    int g = blockIdx.x, t = threadIdx.x;
    float denom = fmaxf(cntf[g], 1.0f);
    gv[t] = sums[g * 64 + t] / denom;
    __syncthreads();
    if (t < 32) {
        float a = bl1[t];
#pragma unroll
        for (int k = 0; k < 64; ++k) a += gv[k] * Wl1[k * 32 + t];
        hid[t] = fmaxf(a, 0.0f);
    }
    __syncthreads();
    if (t == 0) {
        float o = bl2[0];
#pragma unroll
        for (int k = 0; k < 32; ++k) o += hid[k] * Wl2[k];
        out[g] = o;
    }
}

extern "C" void kernel_launch(void* const* d_in, const int* in_sizes, int n_in,
                              void* d_out, int out_size, void* d_ws, size_t ws_size,
                              hipStream_t stream) {
    const float* x   = (const float*)d_in[0];
    const int* ei    = (const int*)d_in[1];
    const int* batch = (const int*)d_in[2];
    const float* W1  = (const float*)d_in[3];
    const float* b1  = (const float*)d_in[4];
    const float* W2  = (const float*)d_in[5];
    const float* b2  = (const float*)d_in[6];
    const float* W3  = (const float*)d_in[7];
    const float* b3  = (const float*)d_in[8];
    const float* Wl1 = (const float*)d_in[9];
    const float* bl1 = (const float*)d_in[10];
    const float* Wl2 = (const float*)d_in[11];
    const float* bl2 = (const float*)d_in[12];
    float* out = (float*)d_out;

    const int N = N_NODES;
    const int E = in_sizes[1] / 2;   // 3.2M
    const int* src = ei;
    const int* dst = ei + E;

    char* ws = (char*)d_ws;
    float* sums    = (float*)(ws + OFF_SUMS);
    float* cntf    = (float*)(ws + OFF_CNTF);
    int*   hist    = (int*)(ws + OFF_HIST);
    int*   bsum    = (int*)(ws + OFF_BSUM);
    int*   row_ptr = (int*)(ws + OFF_ROWPTR);
    float* dinv    = (float*)(ws + OFF_DINV);
    int*   col     = (int*)(ws + OFF_COL);
    unsigned short* xs1 = (unsigned short*)(ws + OFF_XS1);   // bf16
    float* bufQ    = (float*)(ws + OFF_BUFQ);   // bf16 xs2, later fp32 z3
    float* bufR    = (float*)(ws + OFF_BUFR);   // bf16 z2, later bf16 ys
    float* bufP    = (float*)(ws + OFF_BUFP);   // bf16 h2
    int*   packed  = (int*)(ws + OFF_PAIRS);    // aliases bufP (dead before h2)

    // CSR build: hist(+zero) -> scanA -> bin -> csr(+xs1 scale, LDS-staged col)
    int epb = (E + NBLK - 1) / NBLK;   // 12500
    hist_kernel<<<NBLK, 256, 0, stream>>>(dst, hist, (int*)ws, E, epb);
    scanhA_kernel<<<SCAN_BLKS, 1024, 0, stream>>>(hist, bsum);
    bin_kernel<<<NBLK, 256, 0, stream>>>(src, dst, hist, bsum, packed, E, epb);
    csr_kernel<<<NB_BUCKETS, 512, 0, stream>>>(packed, hist, bsum, x,
                                               row_ptr, dinv, xs1, col, E);

    // Layer 1 (agg + gemm1 fused): xs2(bf16) = dinv*relu((agg xs1)@W1+b1)
    agg8g1_kernel<<<(N + 3) / 4, 256, 0, stream>>>(xs1, row_ptr, col, dinv, W1, b1,
                                                   (unsigned short*)bufQ, N);

    // Layer 2: z2(bf16) = agg_bf16(xs2) [4 quarter-dispatches: diagnostic]
    const int Q = 25000;   // quarter of N
    for (int q = 0; q < 4; ++q) {
        int n0 = q * Q, n1 = min(n0 + Q, N);
        agg64bf_kernel<true><<<(n1 - n0 + 3) / 4, 256, 0, stream>>>(
            (const unsigned short*)bufQ, row_ptr, col, dinv, bufR, n0, n1);
    }
    gemm_kernel<64, 128, true, true, false, true, true><<<3125, 256, 0, stream>>>(
        bufR, W2, b2, nullptr, bufP, N);

    // Layer 3: ys(bf16) = dinv*(h2@W3) ; z3(fp32) = agg_bf16(ys) [quartered]
    gemm_kernel<128, 64, false, false, true, true, true><<<1563, 256, 0, stream>>>(
        bufP, W3, nullptr, dinv, bufR, N);
    for (int q = 0; q < 4; ++q) {
        int n0 = q * Q, n1 = min(n0 + Q, N);
        agg64bf_kernel<false><<<(n1 - n0 + 3) / 4, 256, 0, stream>>>(
            (const unsigned short*)bufR, row_ptr, col, dinv, bufQ, n0, n1);
    }

    // Pool + MLP head
    pool_kernel<<<(N + POOL_NPB - 1) / POOL_NPB, 256, 0, stream>>>(bufQ, b3, batch, sums, cntf, N);
    mlp_kernel<<<N_GRAPHS, 64, 0, stream>>>(sums, cntf, Wl1, bl1, Wl2, bl2, out);
}

// Round 7
// 406.833 us; speedup vs baseline: 1.7901x; 1.0584x over previous
//
#include <hip/hip_runtime.h>
#include <hip/hip_bf16.h>

#define N_NODES 100000
#define N_EDGES 3200000
#define N_GRAPHS 256
#define NB_BUCKETS 196      // ceil(100000 / 512)
#define BSHIFT 9            // 512 nodes per bucket
#define NBLK 256            // blocks for hist/bin passes
#define SCAN_BLKS 49        // 50176 / 1024
#define CSR_CAP 22528       // LDS staging capacity (88 KB); avg bucket 16.4K edges

// ---------------- workspace layout (bytes) ----------------
#define OFF_SUMS      0u            // float[256*64] pool sums (zeroed in hist)
#define OFF_CNTF      65536u        // float[256] pool counts (zeroed in hist)
#define ZERO_BYTES    66560u
#define OFF_HIST      66560u        // int[196*256] (bucket-major) per-(bucket,block) counts
#define OFF_BSUM      267264u       // int[64] scan block sums
#define OFF_ROWPTR    267776u       // int[N+1]
#define OFF_DINV      668160u       // float[N]
#define OFF_COL       1068544u     // int[E]
#define OFF_XS1       13868544u     // bf16[N*8]
#define OFF_BUFQ      20268544u     // bf16 xs2 [N*64], later fp32 z3 [N*64]
#define OFF_BUFR      45868544u     // bf16 z2 [N*64], later bf16 ys [N*64]
#define OFF_BUFP      71468544u     // bf16 h2 [N*128]; ALIASED: packed[E] (dead before h2)
#define OFF_PAIRS     OFF_BUFP
// total ~97 MB

// round-to-nearest-even float -> bf16 (values are finite; no NaN guard needed)
__device__ __forceinline__ unsigned short f2bf(float f) {
    unsigned u = __float_as_uint(f);
    return (unsigned short)((u + 0x7fffu + ((u >> 16) & 1u)) >> 16);
}

// unpack uint4 (8 bf16) and accumulate m * value into a[0..7] (fp32)
__device__ __forceinline__ void acc_bf8(uint4 v, float m, float* a) {
    a[0] += m * __uint_as_float(v.x << 16);
    a[1] += m * __uint_as_float(v.x & 0xffff0000u);
    a[2] += m * __uint_as_float(v.y << 16);
    a[3] += m * __uint_as_float(v.y & 0xffff0000u);
    a[4] += m * __uint_as_float(v.z << 16);
    a[5] += m * __uint_as_float(v.z & 0xffff0000u);
    a[6] += m * __uint_as_float(v.w << 16);
    a[7] += m * __uint_as_float(v.w & 0xffff0000u);
}

// ---- P1: per-(bucket,block) histogram of dst. Also zeroes the pool
// accumulators.
__global__ __launch_bounds__(256) void hist_kernel(const int* __restrict__ dst,
                                                   int* __restrict__ hist,
                                                   int* __restrict__ zbase,
                                                   int E, int epb) {
    __shared__ int h[NB_BUCKETS];
    int t = threadIdx.x, blk = blockIdx.x;
    int gid = blk * 256 + t;
    if (gid < (int)(ZERO_BYTES / 4)) zbase[gid] = 0;
    if (t < NB_BUCKETS) h[t] = 0;
    __syncthreads();
    int e0 = blk * epb, e1 = min(e0 + epb, E);
    for (int e = e0 + t; e < e1; e += 256)
        atomicAdd(&h[__builtin_nontemporal_load(&dst[e]) >> BSHIFT], 1);
    __syncthreads();
    if (t < NB_BUCKETS) hist[t * NBLK + blk] = h[t];
}

// ---- P2: block-local exclusive scan of hist[50176] + per-block sums.
__global__ __launch_bounds__(1024) void scanhA_kernel(int* __restrict__ hist,
                                                      int* __restrict__ bsum) {
    __shared__ int s[1024];
    int t = threadIdx.x;
    int i = blockIdx.x * 1024 + t;     // 49*1024 == 50176 exactly
    int v = hist[i];
    s[t] = v;
    __syncthreads();
    for (int off = 1; off < 1024; off <<= 1) {
        int add = (t >= off) ? s[t - off] : 0;
        __syncthreads();
        s[t] += add;
        __syncthreads();
    }
    hist[i] = s[t] - v;                // block-local exclusive
    if (t == 1023) bsum[blockIdx.x] = s[t];
}

// ---- P3: bin edges, PACKED (dl<<17 | src), local offset scan.
__global__ __launch_bounds__(256) void bin_kernel(const int* __restrict__ src,
                                                  const int* __restrict__ dst,
                                                  const int* __restrict__ hist,
                                                  const int* __restrict__ bsum,
                                                  int* __restrict__ packed, int E, int epb) {
    __shared__ int cur[NB_BUCKETS];
    __shared__ int boffL[SCAN_BLKS];
    int t = threadIdx.x, blk = blockIdx.x;
    if (t < 64) {
        int orig = (t < SCAN_BLKS) ? bsum[t] : 0;
        int v = orig;
        for (int off = 1; off < 64; off <<= 1) {
            int up = __shfl_up(v, off);
            if (t >= off) v += up;
        }
        if (t < SCAN_BLKS) boffL[t] = v - orig;   // exclusive
    }
    __syncthreads();
    if (t < NB_BUCKETS) {
        int i = t * NBLK + blk;
        cur[t] = hist[i] + boffL[i >> 10];
    }
    __syncthreads();
    int e0 = blk * epb, e1 = min(e0 + epb, E);
    for (int e = e0 + t; e < e1; e += 256) {
        int d = __builtin_nontemporal_load(&dst[e]);
        int sv = __builtin_nontemporal_load(&src[e]);
        int pos = atomicAdd(&cur[d >> BSHIFT], 1);
        packed[pos] = ((d & 511) << 17) | sv;
    }
}

// ---- P4: per-bucket CSR finalize + xs1 = bf16(dinv*x).
__global__ __launch_bounds__(512) void csr_kernel(const int* __restrict__ packed,
                                                  const int* __restrict__ hist,
                                                  const int* __restrict__ bsum,
                                                  const float* __restrict__ x,
                                                  int* __restrict__ row_ptr,
                                                  float* __restrict__ dinv,
                                                  unsigned short* __restrict__ xs1,
                                                  int* __restrict__ col, int E) {
    __shared__ int cntL[512];
    __shared__ int rsL[512];
    __shared__ int fillL[512];
    __shared__ int boffL[SCAN_BLKS];
    __shared__ int srcL[CSR_CAP];   // 88 KB staging
    int t = threadIdx.x, b = blockIdx.x;
    int lo = b << BSHIFT;
    int nloc = min(512, N_NODES - lo);
    cntL[t] = 0;
    fillL[t] = 0;
    if (t < 64) {
        int orig = (t < SCAN_BLKS) ? bsum[t] : 0;
        int v = orig;
        for (int off = 1; off < 64; off <<= 1) {
            int up = __shfl_up(v, off);
            if (t >= off) v += up;
        }
        if (t < SCAN_BLKS) boffL[t] = v - orig;   // exclusive
    }
    __syncthreads();
    int i0 = b * NBLK;
    int start = hist[i0] + boffL[i0 >> 10];
    int end;
    if (b == NB_BUCKETS - 1) end = E;
    else {
        int i1 = (b + 1) * NBLK;
        end = hist[i1] + boffL[i1 >> 10];
    }
    for (int e = start + t; e < end; e += 512)
        atomicAdd(&cntL[packed[e] >> 17], 1);
    __syncthreads();
    int v = cntL[t];
    __syncthreads();
    for (int off = 1; off < 512; off <<= 1) {     // inclusive scan (Hillis-Steele)
        int add = (t >= off) ? cntL[t - off] : 0;
        __syncthreads();
        cntL[t] += add;
        __syncthreads();
    }
    int rowstart = start + cntL[t] - v;           // exclusive + bucket base
    rsL[t] = rowstart;
    if (t < nloc) {
        int node = lo + t;
        row_ptr[node] = rowstart;
        float d = rsqrtf((float)(v + 1));
        dinv[node] = d;
        const float4* xv = reinterpret_cast<const float4*>(x) + node * 2;
        float4 xa = xv[0], xb = xv[1];
        uint4 p;
        p.x = (unsigned)f2bf(xa.x * d) | ((unsigned)f2bf(xa.y * d) << 16);
        p.y = (unsigned)f2bf(xa.z * d) | ((unsigned)f2bf(xa.w * d) << 16);
        p.z = (unsigned)f2bf(xb.x * d) | ((unsigned)f2bf(xb.y * d) << 16);
        p.w = (unsigned)f2bf(xb.z * d) | ((unsigned)f2bf(xb.w * d) << 16);
        *reinterpret_cast<uint4*>(&xs1[node * 8]) = p;
    }
    if (b == NB_BUCKETS - 1 && t == 0) row_ptr[N_NODES] = E;
    __syncthreads();
    for (int e = start + t; e < end; e += 512) {
        int p = packed[e];
        int dl = p >> 17;
        int pos = rsL[dl] + atomicAdd(&fillL[dl], 1);
        int rel = pos - start;
        if (rel < CSR_CAP) srcL[rel] = p & 0x1FFFF;
        else col[pos] = p & 0x1FFFF;          // overflow fallback
    }
    __syncthreads();
    int lim = min(end - start, CSR_CAP);
    for (int i = t; i < lim; i += 512)
        col[start + i] = srcL[i];             // coalesced write-out
}

// Layer-1 aggregation FUSED with gemm1 (R4 form: 1 lane = 1 edge, bf16 xs1).
__global__ __launch_bounds__(256) void agg8g1_kernel(
        const unsigned short* __restrict__ xs, const int* __restrict__ row_ptr,
        const int* __restrict__ col, const float* __restrict__ dinv,
        const float* __restrict__ W1, const float* __restrict__ b1,
        unsigned short* __restrict__ xs2, int n) {
    int wave = threadIdx.x >> 6;            // 4 waves/block = 4 nodes/block
    int node = blockIdx.x * 4 + wave;
    if (node >= n) return;
    int lane = threadIdx.x & 63;
    float w[8];
    float bias = b1[lane];
#pragma unroll
    for (int k = 0; k < 8; ++k) w[k] = W1[k * 64 + lane];   // L2-broadcast
    int e0 = row_ptr[node], e1 = row_ptr[node + 1];
    float a[8] = {0.f, 0.f, 0.f, 0.f, 0.f, 0.f, 0.f, 0.f};
    uint4 sv = *reinterpret_cast<const uint4*>(&xs[node * 8]);   // uniform
    int base = e0;
    for (; base + 64 <= e1; base += 64) {   // deg > 64: ~3e-7 of rows
        int c = __builtin_nontemporal_load(&col[base + lane]);
        uint4 v = *reinterpret_cast<const uint4*>(&xs[c * 8]);
        acc_bf8(v, 1.f, a);
    }
    if (base < e1) {                        // single masked pass (<=64 edges)
        int e = base + lane;
        int c = __builtin_nontemporal_load(&col[min(e, e1 - 1)]);
        uint4 v = *reinterpret_cast<const uint4*>(&xs[c * 8]);
        acc_bf8(v, (e < e1) ? 1.f : 0.f, a);
    }
    acc_bf8(sv, (lane == 0) ? 1.f : 0.f, a);   // self-loop, counted once
    // octet reduce: a[k] summed over the 8 lanes of this octet
#pragma unroll
    for (int k = 0; k < 8; ++k) {
        a[k] += __shfl_xor(a[k], 1);
        a[k] += __shfl_xor(a[k], 2);
        a[k] += __shfl_xor(a[k], 4);
    }
    // cross-octet reduce on one value per lane (feature = lane&7)
    float v8 = a[lane & 7];
    v8 += __shfl_xor(v8, 8);
    v8 += __shfl_xor(v8, 16);
    v8 += __shfl_xor(v8, 32);
    float d = dinv[node];
    float acc = bias;
#pragma unroll
    for (int k = 0; k < 8; ++k) acc += (__shfl(v8, k) * d) * w[k];
    xs2[node * 64 + lane] = f2bf(d * fmaxf(acc, 0.0f));
}

// D=64 aggregation over a bf16 feature table (rows = 128 B).
// Single-shot whole-row issue. BF16OUT: z stored as bf16.
template <bool BF16OUT>
__global__ __launch_bounds__(256) void agg64bf_kernel(
        const unsigned short* __restrict__ xs, const int* __restrict__ row_ptr,
        const int* __restrict__ col, const float* __restrict__ dinv,
        float* __restrict__ z, int n0, int n1) {
    int wave = threadIdx.x >> 6;            // 4 waves/block = 4 nodes/block
    int node = n0 + blockIdx.x * 4 + wave;
    if (node >= n1) return;
    int lane = threadIdx.x & 63;
    int j = lane >> 3, l = lane & 7;
    int e0 = row_ptr[node], e1 = row_ptr[node + 1];
    float a[8] = {0.f, 0.f, 0.f, 0.f, 0.f, 0.f, 0.f, 0.f};
    // self-row load issued first: shares the col-load wait
    uint4 sv = *reinterpret_cast<const uint4*>(&xs[node * 64 + 8 * l]);
    int base = e0;
    // rare fallback: keep remaining <= 48 edges (Poisson(32): ~0.2% of rows)
    for (; e1 - base > 48; base += 32) {
        int s0 = __builtin_nontemporal_load(&col[base + j]);
        int s1 = __builtin_nontemporal_load(&col[base + 8 + j]);
        int s2 = __builtin_nontemporal_load(&col[base + 16 + j]);
        int s3 = __builtin_nontemporal_load(&col[base + 24 + j]);
        uint4 v0 = *reinterpret_cast<const uint4*>(&xs[s0 * 64 + 8 * l]);
        uint4 v1 = *reinterpret_cast<const uint4*>(&xs[s1 * 64 + 8 * l]);
        uint4 v2 = *reinterpret_cast<const uint4*>(&xs[s2 * 64 + 8 * l]);
        uint4 v3 = *reinterpret_cast<const uint4*>(&xs[s3 * 64 + 8 * l]);
        acc_bf8(v0, 1.f, a); acc_bf8(v1, 1.f, a);
        acc_bf8(v2, 1.f, a); acc_bf8(v3, 1.f, a);
    }
    int rem = e1 - base;   // wave-uniform, 0..48
    if (rem > 0) {
        int e1m1 = e1 - 1;
        bool g4 = rem > 32, g5 = rem > 40;   // wave-uniform guards
        int i0 = base + j,      i1 = base + 8 + j;
        int i2 = base + 16 + j, i3 = base + 24 + j;
        int i4 = base + 32 + j, i5 = base + 40 + j;
        // all col loads issued back-to-back (clamped -> always in-bounds)
        int c0 = __builtin_nontemporal_load(&col[min(i0, e1m1)]);
        int c1 = __builtin_nontemporal_load(&col[min(i1, e1m1)]);
        int c2 = __builtin_nontemporal_load(&col[min(i2, e1m1)]);
        int c3 = __builtin_nontemporal_load(&col[min(i3, e1m1)]);
        int c4 = 0, c5 = 0;
        if (g4) c4 = __builtin_nontemporal_load(&col[min(i4, e1m1)]);
        if (g5) c5 = __builtin_nontemporal_load(&col[min(i5, e1m1)]);
        // all gathers issued back-to-back (progressive counted vmcnt waits)
        uint4 v0 = *reinterpret_cast<const uint4*>(&xs[c0 * 64 + 8 * l]);
        uint4 v1 = *reinterpret_cast<const uint4*>(&xs[c1 * 64 + 8 * l]);
        uint4 v2 = *reinterpret_cast<const uint4*>(&xs[c2 * 64 + 8 * l]);
        uint4 v3 = *reinterpret_cast<const uint4*>(&xs[c3 * 64 + 8 * l]);
        uint4 v4, v5;
        if (g4) v4 = *reinterpret_cast<const uint4*>(&xs[c4 * 64 + 8 * l]);
        if (g5) v5 = *reinterpret_cast<const uint4*>(&xs[c5 * 64 + 8 * l]);
        acc_bf8(v0, (i0 < e1) ? 1.f : 0.f, a);
        acc_bf8(v1, (i1 < e1) ? 1.f : 0.f, a);
        acc_bf8(v2, (i2 < e1) ? 1.f : 0.f, a);
        acc_bf8(v3, (i3 < e1) ? 1.f : 0.f, a);
        if (g4) acc_bf8(v4, (i4 < e1) ? 1.f : 0.f, a);
        if (g5) acc_bf8(v5, (i5 < e1) ? 1.f : 0.f, a);
    }
    acc_bf8(sv, (j == 0) ? 1.f : 0.f, a);   // self-loop term, counted once
#pragma unroll
    for (int k = 0; k < 8; ++k) {
        a[k] += __shfl_xor(a[k], 8);
        a[k] += __shfl_xor(a[k], 16);
        a[k] += __shfl_xor(a[k], 32);
    }
    if (j == 0) {
        float d = dinv[node];
        if constexpr (BF16OUT) {
            unsigned short* zh = reinterpret_cast<unsigned short*>(z);
            uint4 p;
            p.x = (unsigned)f2bf(a[0] * d) | ((unsigned)f2bf(a[1] * d) << 16);
            p.y = (unsigned)f2bf(a[2] * d) | ((unsigned)f2bf(a[3] * d) << 16);
            p.z = (unsigned)f2bf(a[4] * d) | ((unsigned)f2bf(a[5] * d) << 16);
            p.w = (unsigned)f2bf(a[6] * d) | ((unsigned)f2bf(a[7] * d) << 16);
            *reinterpret_cast<uint4*>(&zh[node * 64 + 8 * l]) = p;
        } else {
            float4 r0 = {a[0] * d, a[1] * d, a[2] * d, a[3] * d};
            float4 r1 = {a[4] * d, a[5] * d, a[6] * d, a[7] * d};
            *reinterpret_cast<float4*>(&z[node * 64 + 8 * l]) = r0;
            *reinterpret_cast<float4*>(&z[node * 64 + 8 * l + 4]) = r1;
        }
    }
}

// Y[row,:] = opt_scale(dinv) * opt_relu( X@W + opt_bias ), X is bf16 global.
// RESTRUCTURED (R6): RR=8 rows x 4 cols per thread -> 2x FMAs per LDS read;
// XBF16LDS: X tile kept raw bf16 in LDS (halves tile, unpack at read).
// Per 4-k step: 4 W-reads (512B bursts) + RR X-reads (broadcast across
// col-groups) feeding 16*RR FMAs -> LDS no longer oversubscribes 4 SIMDs.
template <int K, int M, int RR, bool BIAS, bool RELU, bool SCALE, bool XBF16LDS, bool BF16OUT>
__global__ __launch_bounds__(256) void gemm_kernel(
        const unsigned short* __restrict__ X, const float* __restrict__ W,
        const float* __restrict__ b, const float* __restrict__ dinv,
        float* __restrict__ Y, int nrows) {
    constexpr int CG = M / 4;          // col-groups  (gemm2: 32, gemm3: 16)
    constexpr int RG = 256 / CG;       // row-groups  (gemm2: 8,  gemm3: 16)
    constexpr int ROWS = RG * RR;      // rows/tile   (gemm2: 64, gemm3: 128)
    constexpr int XSTR = XBF16LDS ? (K + 8) : (K + 4);  // 16B-aligned rows
    __shared__ float Wl[K * M];        // 32 KB
    __shared__ float Bl[M];
    __shared__ __align__(16) unsigned char Xraw[ROWS * XSTR * (XBF16LDS ? 2 : 4)];
    float* Xlf = reinterpret_cast<float*>(Xraw);
    unsigned short* Xlh = reinterpret_cast<unsigned short*>(Xraw);
    int tid = threadIdx.x;
    {   // float4 weight staging
        const float4* Wv = reinterpret_cast<const float4*>(W);
        float4* Wlv = reinterpret_cast<float4*>(Wl);
        for (int i = tid; i < K * M / 4; i += 256) Wlv[i] = Wv[i];
    }
    if (tid < M) Bl[tid] = BIAS ? b[tid] : 0.0f;
    int cg = tid % CG;
    int rg = tid / CG;
    int ntiles = (nrows + ROWS - 1) / ROWS;
    for (int tile = blockIdx.x; tile < ntiles; tile += gridDim.x) {
        int row0 = tile * ROWS;
        __syncthreads();
        if constexpr (XBF16LDS) {   // raw bf16 copy, 8 elems per uint4
            const uint4* Xg = reinterpret_cast<const uint4*>(X);
            int base8 = row0 * (K / 8);
            int tot8 = nrows * (K / 8);
            for (int i = tid; i < ROWS * K / 8; i += 256) {
                uint4 v = {0u, 0u, 0u, 0u};
                if (base8 + i < tot8) v = Xg[base8 + i];
                int rr = i / (K / 8), kk = i % (K / 8);
                *reinterpret_cast<uint4*>(&Xlh[rr * XSTR + kk * 8]) = v;
            }
        } else {                    // expand bf16 -> fp32 at staging
            const uint2* Xg = reinterpret_cast<const uint2*>(X);
            int base4 = row0 * (K / 4);
            int tot4 = nrows * (K / 4);
            for (int i = tid; i < ROWS * K / 4; i += 256) {
                float4 v = {0.f, 0.f, 0.f, 0.f};
                if (base4 + i < tot4) {
                    uint2 raw = Xg[base4 + i];
                    v.x = __uint_as_float(raw.x << 16);
                    v.y = __uint_as_float(raw.x & 0xffff0000u);
                    v.z = __uint_as_float(raw.y << 16);
                    v.w = __uint_as_float(raw.y & 0xffff0000u);
                }
                int rr = i / (K / 4), kk = i % (K / 4);
                *reinterpret_cast<float4*>(&Xlf[rr * XSTR + kk * 4]) = v;
            }
        }
        __syncthreads();
        float4 acc[RR];
#pragma unroll
        for (int rr = 0; rr < RR; ++rr)
            acc[rr] = *reinterpret_cast<const float4*>(&Bl[cg * 4]);
#pragma unroll 1
        for (int k = 0; k < K; k += 4) {
            const float4 w0 = *reinterpret_cast<const float4*>(&Wl[(k + 0) * M + cg * 4]);
            const float4 w1 = *reinterpret_cast<const float4*>(&Wl[(k + 1) * M + cg * 4]);
            const float4 w2 = *reinterpret_cast<const float4*>(&Wl[(k + 2) * M + cg * 4]);
            const float4 w3 = *reinterpret_cast<const float4*>(&Wl[(k + 3) * M + cg * 4]);
#pragma unroll
            for (int rr = 0; rr < RR; ++rr) {
                float4 xv;
                if constexpr (XBF16LDS) {
                    uint2 xr = *reinterpret_cast<const uint2*>(
                        &Xlh[(rg * RR + rr) * XSTR + k]);
                    xv.x = __uint_as_float(xr.x << 16);
                    xv.y = __uint_as_float(xr.x & 0xffff0000u);
                    xv.z = __uint_as_float(xr.y << 16);
                    xv.w = __uint_as_float(xr.y & 0xffff0000u);
                } else {
                    xv = *reinterpret_cast<const float4*>(
                        &Xlf[(rg * RR + rr) * XSTR + k]);
                }
                acc[rr].x += xv.x * w0.x + xv.y * w1.x + xv.z * w2.x + xv.w * w3.x;
                acc[rr].y += xv.x * w0.y + xv.y * w1.y + xv.z * w2.y + xv.w * w3.y;
                acc[rr].z += xv.x * w0.z + xv.y * w1.z + xv.z * w2.z + xv.w * w3.z;
                acc[rr].w += xv.x * w0.w + xv.y * w1.w + xv.z * w2.w + xv.w * w3.w;
            }
        }
#pragma unroll
        for (int rr = 0; rr < RR; ++rr) {
            int row = row0 + rg * RR + rr;
            if (row < nrows) {
                float4 a = acc[rr];
                if constexpr (RELU) {
                    a.x = fmaxf(a.x, 0.f); a.y = fmaxf(a.y, 0.f);
                    a.z = fmaxf(a.z, 0.f); a.w = fmaxf(a.w, 0.f);
                }
                if constexpr (SCALE) {
                    float d = dinv[row];
                    a.x *= d; a.y *= d; a.z *= d; a.w *= d;
                }
                if constexpr (BF16OUT) {
                    unsigned short* Yh = reinterpret_cast<unsigned short*>(Y);
                    uint2 p;
                    p.x = (unsigned)f2bf(a.x) | ((unsigned)f2bf(a.y) << 16);
                    p.y = (unsigned)f2bf(a.z) | ((unsigned)f2bf(a.w) << 16);
                    *reinterpret_cast<uint2*>(&Yh[row * M + cg * 4]) = p;
                } else {
                    *reinterpret_cast<float4*>(&Y[row * M + cg * 4]) = a;
                }
            }
        }
    }
}

// h3 = relu(z3 + b3); pool sums/counts per graph (R18 proven form).
#define POOL_NPB 128   // nodes per block (32 per wave, contiguous)
__global__ __launch_bounds__(256) void pool_kernel(
        const float* __restrict__ z3, const float* __restrict__ b3,
        const int* __restrict__ batch, float* __restrict__ sums,
        float* __restrict__ cntf, int n) {
    int wave = threadIdx.x >> 6;
    int lane = threadIdx.x & 63;   // feature index
    int node0 = blockIdx.x * POOL_NPB + wave * 32;
    int nodeEnd = min(node0 + 32, n);
    if (node0 >= n) return;
    float bias = b3[lane];
    float acc = 0.0f, cnt = 0.0f;
    int curg = -1;
    for (int node = node0; node < nodeEnd; ++node) {
        int g = batch[node];               // wave-uniform (lane = feature)
        if (g != curg) {                   // wave-uniform branch
            if (curg >= 0) {
                atomicAdd(&sums[curg * 64 + lane], acc);
                if (lane == 0) atomicAdd(&cntf[curg], cnt);
            }
            curg = g; acc = 0.0f; cnt = 0.0f;
        }
        acc += fmaxf(__builtin_nontemporal_load(&z3[node * 64 + lane]) + bias, 0.0f);
        cnt += 1.0f;
    }
    if (curg >= 0) {
        atomicAdd(&sums[curg * 64 + lane], acc);
        if (lane == 0) atomicAdd(&cntf[curg], cnt);
    }
}

// per-graph: g = sums/max(cnt,1); hid = relu(g@Wl1+bl1); out = hid@Wl2+bl2
__global__ void mlp_kernel(const float* __restrict__ sums, const float* __restrict__ cntf,
                           const float* __restrict__ Wl1, const float* __restrict__ bl1,
                           const float* __restrict__ Wl2, const float* __restrict__ bl2,
                           float* __restrict__ out) {
    __shared__ float gv[64];
    __shared__ float hid[32];
    int g = blockIdx.x, t = threadIdx.x;
    float denom = fmaxf(cntf[g], 1.0f);
    gv[t] = sums[g * 64 + t] / denom;
    __syncthreads();
    if (t < 32) {
        float a = bl1[t];
#pragma unroll
        for (int k = 0; k < 64; ++k) a += gv[k] * Wl1[k * 32 + t];
        hid[t] = fmaxf(a, 0.0f);
    }
    __syncthreads();
    if (t == 0) {
        float o = bl2[0];
#pragma unroll
        for (int k = 0; k < 32; ++k) o += hid[k] * Wl2[k];
        out[g] = o;
    }
}

extern "C" void kernel_launch(void* const* d_in, const int* in_sizes, int n_in,
                              void* d_out, int out_size, void* d_ws, size_t ws_size,
                              hipStream_t stream) {
    const float* x   = (const float*)d_in[0];
    const int* ei    = (const int*)d_in[1];
    const int* batch = (const int*)d_in[2];
    const float* W1  = (const float*)d_in[3];
    const float* b1  = (const float*)d_in[4];
    const float* W2  = (const float*)d_in[5];
    const float* b2  = (const float*)d_in[6];
    const float* W3  = (const float*)d_in[7];
    const float* b3  = (const float*)d_in[8];
    const float* Wl1 = (const float*)d_in[9];
    const float* bl1 = (const float*)d_in[10];
    const float* Wl2 = (const float*)d_in[11];
    const float* bl2 = (const float*)d_in[12];
    float* out = (float*)d_out;

    const int N = N_NODES;
    const int E = in_sizes[1] / 2;   // 3.2M
    const int* src = ei;
    const int* dst = ei + E;

    char* ws = (char*)d_ws;
    float* sums    = (float*)(ws + OFF_SUMS);
    float* cntf    = (float*)(ws + OFF_CNTF);
    int*   hist    = (int*)(ws + OFF_HIST);
    int*   bsum    = (int*)(ws + OFF_BSUM);
    int*   row_ptr = (int*)(ws + OFF_ROWPTR);
    float* dinv    = (float*)(ws + OFF_DINV);
    int*   col     = (int*)(ws + OFF_COL);
    unsigned short* xs1 = (unsigned short*)(ws + OFF_XS1);   // bf16
    float* bufQ    = (float*)(ws + OFF_BUFQ);   // bf16 xs2, later fp32 z3
    float* bufR    = (float*)(ws + OFF_BUFR);   // bf16 z2, later bf16 ys
    float* bufP    = (float*)(ws + OFF_BUFP);   // bf16 h2
    int*   packed  = (int*)(ws + OFF_PAIRS);    // aliases bufP (dead before h2)

    // CSR build: hist(+zero) -> scanA -> bin -> csr(+xs1 scale, LDS-staged col)
    int epb = (E + NBLK - 1) / NBLK;   // 12500
    hist_kernel<<<NBLK, 256, 0, stream>>>(dst, hist, (int*)ws, E, epb);
    scanhA_kernel<<<SCAN_BLKS, 1024, 0, stream>>>(hist, bsum);
    bin_kernel<<<NBLK, 256, 0, stream>>>(src, dst, hist, bsum, packed, E, epb);
    csr_kernel<<<NB_BUCKETS, 512, 0, stream>>>(packed, hist, bsum, x,
                                               row_ptr, dinv, xs1, col, E);

    // Layer 1 (agg + gemm1 fused): xs2(bf16) = dinv*relu((agg xs1)@W1+b1)
    agg8g1_kernel<<<(N + 3) / 4, 256, 0, stream>>>(xs1, row_ptr, col, dinv, W1, b1,
                                                   (unsigned short*)bufQ, N);

    // Layer 2: z2(bf16) = agg_bf16(xs2) ; h2(bf16) = relu(z2@W2+b2)
    agg64bf_kernel<true><<<(N + 3) / 4, 256, 0, stream>>>(
        (const unsigned short*)bufQ, row_ptr, col, dinv, bufR, 0, N);
    gemm_kernel<64, 128, 8, true, true, false, false, true><<<1563, 256, 0, stream>>>(
        (const unsigned short*)bufR, W2, b2, nullptr, bufP, N);

    // Layer 3: ys(bf16) = dinv*(h2@W3) ; z3(fp32) = agg_bf16(ys)
    gemm_kernel<128, 64, 8, false, false, true, true, true><<<782, 256, 0, stream>>>(
        (const unsigned short*)bufP, W3, nullptr, dinv, bufR, N);
    agg64bf_kernel<false><<<(N + 3) / 4, 256, 0, stream>>>(
        (const unsigned short*)bufR, row_ptr, col, dinv, bufQ, 0, N);

    // Pool + MLP head
    pool_kernel<<<(N + POOL_NPB - 1) / POOL_NPB, 256, 0, stream>>>(bufQ, b3, batch, sums, cntf, N);
    mlp_kernel<<<N_GRAPHS, 64, 0, stream>>>(sums, cntf, Wl1, bl1, Wl2, bl2, out);
}

// Round 8
// 356.161 us; speedup vs baseline: 2.0448x; 1.1423x over previous
//
#include <hip/hip_runtime.h>
#include <hip/hip_bf16.h>

#define N_NODES 100000
#define N_EDGES 3200000
#define N_GRAPHS 256
#define NB_BUCKETS 196      // ceil(100000 / 512)
#define BSHIFT 9            // 512 nodes per bucket
#define NBLK 256            // blocks for hist/bin passes
#define SCAN_BLKS 49        // 50176 / 1024
#define CSR_CAP 22528       // LDS staging capacity (88 KB); avg bucket 16.4K edges

// ---------------- workspace layout (bytes) ----------------
#define OFF_SUMS      0u            // float[256*64] pool sums (zeroed in hist)
#define OFF_CNTF      65536u        // float[256] pool counts (zeroed in hist)
#define ZERO_BYTES    66560u
#define OFF_HIST      66560u        // int[196*256] (bucket-major) per-(bucket,block) counts
#define OFF_BSUM      267264u       // int[64] scan block sums
#define OFF_ROWPTR    267776u       // int[N+1]
#define OFF_DINV      668160u       // float[N]
#define OFF_COL       1068544u     // int[E]
#define OFF_XS1       13868544u     // bf16[N*8]
#define OFF_BUFQ      20268544u     // bf16 xs2 [N*64], later fp32 z3 [N*64]
#define OFF_BUFR      45868544u     // bf16 z2 [N*64], later bf16 ys [N*64]
#define OFF_BUFP      71468544u     // bf16 h2 [N*128]; ALIASED: packed[E] (dead before h2)
#define OFF_PAIRS     OFF_BUFP
// total ~97 MB

typedef __attribute__((ext_vector_type(8))) short bf16x8;   // MFMA A/B frag (4 VGPRs)
typedef __attribute__((ext_vector_type(4))) float f32x4;    // MFMA C/D frag

// round-to-nearest-even float -> bf16 (values are finite; no NaN guard needed)
__device__ __forceinline__ unsigned short f2bf(float f) {
    unsigned u = __float_as_uint(f);
    return (unsigned short)((u + 0x7fffu + ((u >> 16) & 1u)) >> 16);
}

// unpack uint4 (8 bf16) and accumulate m * value into a[0..7] (fp32)
__device__ __forceinline__ void acc_bf8(uint4 v, float m, float* a) {
    a[0] += m * __uint_as_float(v.x << 16);
    a[1] += m * __uint_as_float(v.x & 0xffff0000u);
    a[2] += m * __uint_as_float(v.y << 16);
    a[3] += m * __uint_as_float(v.y & 0xffff0000u);
    a[4] += m * __uint_as_float(v.z << 16);
    a[5] += m * __uint_as_float(v.z & 0xffff0000u);
    a[6] += m * __uint_as_float(v.w << 16);
    a[7] += m * __uint_as_float(v.w & 0xffff0000u);
}

// ---- P1: per-(bucket,block) histogram of dst. Also zeroes the pool
// accumulators.
__global__ __launch_bounds__(256) void hist_kernel(const int* __restrict__ dst,
                                                   int* __restrict__ hist,
                                                   int* __restrict__ zbase,
                                                   int E, int epb) {
    __shared__ int h[NB_BUCKETS];
    int t = threadIdx.x, blk = blockIdx.x;
    int gid = blk * 256 + t;
    if (gid < (int)(ZERO_BYTES / 4)) zbase[gid] = 0;
    if (t < NB_BUCKETS) h[t] = 0;
    __syncthreads();
    int e0 = blk * epb, e1 = min(e0 + epb, E);
    for (int e = e0 + t; e < e1; e += 256)
        atomicAdd(&h[__builtin_nontemporal_load(&dst[e]) >> BSHIFT], 1);
    __syncthreads();
    if (t < NB_BUCKETS) hist[t * NBLK + blk] = h[t];
}

// ---- P2: block-local exclusive scan of hist[50176] + per-block sums.
__global__ __launch_bounds__(1024) void scanhA_kernel(int* __restrict__ hist,
                                                      int* __restrict__ bsum) {
    __shared__ int s[1024];
    int t = threadIdx.x;
    int i = blockIdx.x * 1024 + t;     // 49*1024 == 50176 exactly
    int v = hist[i];
    s[t] = v;
    __syncthreads();
    for (int off = 1; off < 1024; off <<= 1) {
        int add = (t >= off) ? s[t - off] : 0;
        __syncthreads();
        s[t] += add;
        __syncthreads();
    }
    hist[i] = s[t] - v;                // block-local exclusive
    if (t == 1023) bsum[blockIdx.x] = s[t];
}

// ---- P3: bin edges, PACKED (dl<<17 | src), local offset scan.
__global__ __launch_bounds__(256) void bin_kernel(const int* __restrict__ src,
                                                  const int* __restrict__ dst,
                                                  const int* __restrict__ hist,
                                                  const int* __restrict__ bsum,
                                                  int* __restrict__ packed, int E, int epb) {
    __shared__ int cur[NB_BUCKETS];
    __shared__ int boffL[SCAN_BLKS];
    int t = threadIdx.x, blk = blockIdx.x;
    if (t < 64) {
        int orig = (t < SCAN_BLKS) ? bsum[t] : 0;
        int v = orig;
        for (int off = 1; off < 64; off <<= 1) {
            int up = __shfl_up(v, off);
            if (t >= off) v += up;
        }
        if (t < SCAN_BLKS) boffL[t] = v - orig;   // exclusive
    }
    __syncthreads();
    if (t < NB_BUCKETS) {
        int i = t * NBLK + blk;
        cur[t] = hist[i] + boffL[i >> 10];
    }
    __syncthreads();
    int e0 = blk * epb, e1 = min(e0 + epb, E);
    for (int e = e0 + t; e < e1; e += 256) {
        int d = __builtin_nontemporal_load(&dst[e]);
        int sv = __builtin_nontemporal_load(&src[e]);
        int pos = atomicAdd(&cur[d >> BSHIFT], 1);
        packed[pos] = ((d & 511) << 17) | sv;
    }
}

// ---- P4: per-bucket CSR finalize + xs1 = bf16(dinv*x).
__global__ __launch_bounds__(512) void csr_kernel(const int* __restrict__ packed,
                                                  const int* __restrict__ hist,
                                                  const int* __restrict__ bsum,
                                                  const float* __restrict__ x,
                                                  int* __restrict__ row_ptr,
                                                  float* __restrict__ dinv,
                                                  unsigned short* __restrict__ xs1,
                                                  int* __restrict__ col, int E) {
    __shared__ int cntL[512];
    __shared__ int rsL[512];
    __shared__ int fillL[512];
    __shared__ int boffL[SCAN_BLKS];
    __shared__ int srcL[CSR_CAP];   // 88 KB staging
    int t = threadIdx.x, b = blockIdx.x;
    int lo = b << BSHIFT;
    int nloc = min(512, N_NODES - lo);
    cntL[t] = 0;
    fillL[t] = 0;
    if (t < 64) {
        int orig = (t < SCAN_BLKS) ? bsum[t] : 0;
        int v = orig;
        for (int off = 1; off < 64; off <<= 1) {
            int up = __shfl_up(v, off);
            if (t >= off) v += up;
        }
        if (t < SCAN_BLKS) boffL[t] = v - orig;   // exclusive
    }
    __syncthreads();
    int i0 = b * NBLK;
    int start = hist[i0] + boffL[i0 >> 10];
    int end;
    if (b == NB_BUCKETS - 1) end = E;
    else {
        int i1 = (b + 1) * NBLK;
        end = hist[i1] + boffL[i1 >> 10];
    }
    for (int e = start + t; e < end; e += 512)
        atomicAdd(&cntL[packed[e] >> 17], 1);
    __syncthreads();
    int v = cntL[t];
    __syncthreads();
    for (int off = 1; off < 512; off <<= 1) {     // inclusive scan (Hillis-Steele)
        int add = (t >= off) ? cntL[t - off] : 0;
        __syncthreads();
        cntL[t] += add;
        __syncthreads();
    }
    int rowstart = start + cntL[t] - v;           // exclusive + bucket base
    rsL[t] = rowstart;
    if (t < nloc) {
        int node = lo + t;
        row_ptr[node] = rowstart;
        float d = rsqrtf((float)(v + 1));
        dinv[node] = d;
        const float4* xv = reinterpret_cast<const float4*>(x) + node * 2;
        float4 xa = xv[0], xb = xv[1];
        uint4 p;
        p.x = (unsigned)f2bf(xa.x * d) | ((unsigned)f2bf(xa.y * d) << 16);
        p.y = (unsigned)f2bf(xa.z * d) | ((unsigned)f2bf(xa.w * d) << 16);
        p.z = (unsigned)f2bf(xb.x * d) | ((unsigned)f2bf(xb.y * d) << 16);
        p.w = (unsigned)f2bf(xb.z * d) | ((unsigned)f2bf(xb.w * d) << 16);
        *reinterpret_cast<uint4*>(&xs1[node * 8]) = p;
    }
    if (b == NB_BUCKETS - 1 && t == 0) row_ptr[N_NODES] = E;
    __syncthreads();
    for (int e = start + t; e < end; e += 512) {
        int p = packed[e];
        int dl = p >> 17;
        int pos = rsL[dl] + atomicAdd(&fillL[dl], 1);
        int rel = pos - start;
        if (rel < CSR_CAP) srcL[rel] = p & 0x1FFFF;
        else col[pos] = p & 0x1FFFF;          // overflow fallback
    }
    __syncthreads();
    int lim = min(end - start, CSR_CAP);
    for (int i = t; i < lim; i += 512)
        col[start + i] = srcL[i];             // coalesced write-out
}

// Layer-1 aggregation FUSED with gemm1 (R4 form: 1 lane = 1 edge, bf16 xs1).
__global__ __launch_bounds__(256) void agg8g1_kernel(
        const unsigned short* __restrict__ xs, const int* __restrict__ row_ptr,
        const int* __restrict__ col, const float* __restrict__ dinv,
        const float* __restrict__ W1, const float* __restrict__ b1,
        unsigned short* __restrict__ xs2, int n) {
    int wave = threadIdx.x >> 6;            // 4 waves/block = 4 nodes/block
    int node = blockIdx.x * 4 + wave;
    if (node >= n) return;
    int lane = threadIdx.x & 63;
    float w[8];
    float bias = b1[lane];
#pragma unroll
    for (int k = 0; k < 8; ++k) w[k] = W1[k * 64 + lane];   // L2-broadcast
    int e0 = row_ptr[node], e1 = row_ptr[node + 1];
    float a[8] = {0.f, 0.f, 0.f, 0.f, 0.f, 0.f, 0.f, 0.f};
    uint4 sv = *reinterpret_cast<const uint4*>(&xs[node * 8]);   // uniform
    int base = e0;
    for (; base + 64 <= e1; base += 64) {   // deg > 64: ~3e-7 of rows
        int c = __builtin_nontemporal_load(&col[base + lane]);
        uint4 v = *reinterpret_cast<const uint4*>(&xs[c * 8]);
        acc_bf8(v, 1.f, a);
    }
    if (base < e1) {                        // single masked pass (<=64 edges)
        int e = base + lane;
        int c = __builtin_nontemporal_load(&col[min(e, e1 - 1)]);
        uint4 v = *reinterpret_cast<const uint4*>(&xs[c * 8]);
        acc_bf8(v, (e < e1) ? 1.f : 0.f, a);
    }
    acc_bf8(sv, (lane == 0) ? 1.f : 0.f, a);   // self-loop, counted once
    // octet reduce: a[k] summed over the 8 lanes of this octet
#pragma unroll
    for (int k = 0; k < 8; ++k) {
        a[k] += __shfl_xor(a[k], 1);
        a[k] += __shfl_xor(a[k], 2);
        a[k] += __shfl_xor(a[k], 4);
    }
    // cross-octet reduce on one value per lane (feature = lane&7)
    float v8 = a[lane & 7];
    v8 += __shfl_xor(v8, 8);
    v8 += __shfl_xor(v8, 16);
    v8 += __shfl_xor(v8, 32);
    float d = dinv[node];
    float acc = bias;
#pragma unroll
    for (int k = 0; k < 8; ++k) acc += (__shfl(v8, k) * d) * w[k];
    xs2[node * 64 + lane] = f2bf(d * fmaxf(acc, 0.0f));
}

// D=64 aggregation over a bf16 feature table (rows = 128 B).
// Single-shot whole-row issue. BF16OUT: z stored as bf16.
template <bool BF16OUT>
__global__ __launch_bounds__(256) void agg64bf_kernel(
        const unsigned short* __restrict__ xs, const int* __restrict__ row_ptr,
        const int* __restrict__ col, const float* __restrict__ dinv,
        float* __restrict__ z, int n0, int n1) {
    int wave = threadIdx.x >> 6;            // 4 waves/block = 4 nodes/block
    int node = n0 + blockIdx.x * 4 + wave;
    if (node >= n1) return;
    int lane = threadIdx.x & 63;
    int j = lane >> 3, l = lane & 7;
    int e0 = row_ptr[node], e1 = row_ptr[node + 1];
    float a[8] = {0.f, 0.f, 0.f, 0.f, 0.f, 0.f, 0.f, 0.f};
    // self-row load issued first: shares the col-load wait
    uint4 sv = *reinterpret_cast<const uint4*>(&xs[node * 64 + 8 * l]);
    int base = e0;
    // rare fallback: keep remaining <= 48 edges (Poisson(32): ~0.2% of rows)
    for (; e1 - base > 48; base += 32) {
        int s0 = __builtin_nontemporal_load(&col[base + j]);
        int s1 = __builtin_nontemporal_load(&col[base + 8 + j]);
        int s2 = __builtin_nontemporal_load(&col[base + 16 + j]);
        int s3 = __builtin_nontemporal_load(&col[base + 24 + j]);
        uint4 v0 = *reinterpret_cast<const uint4*>(&xs[s0 * 64 + 8 * l]);
        uint4 v1 = *reinterpret_cast<const uint4*>(&xs[s1 * 64 + 8 * l]);
        uint4 v2 = *reinterpret_cast<const uint4*>(&xs[s2 * 64 + 8 * l]);
        uint4 v3 = *reinterpret_cast<const uint4*>(&xs[s3 * 64 + 8 * l]);
        acc_bf8(v0, 1.f, a); acc_bf8(v1, 1.f, a);
        acc_bf8(v2, 1.f, a); acc_bf8(v3, 1.f, a);
    }
    int rem = e1 - base;   // wave-uniform, 0..48
    if (rem > 0) {
        int e1m1 = e1 - 1;
        bool g4 = rem > 32, g5 = rem > 40;   // wave-uniform guards
        int i0 = base + j,      i1 = base + 8 + j;
        int i2 = base + 16 + j, i3 = base + 24 + j;
        int i4 = base + 32 + j, i5 = base + 40 + j;
        // all col loads issued back-to-back (clamped -> always in-bounds)
        int c0 = __builtin_nontemporal_load(&col[min(i0, e1m1)]);
        int c1 = __builtin_nontemporal_load(&col[min(i1, e1m1)]);
        int c2 = __builtin_nontemporal_load(&col[min(i2, e1m1)]);
        int c3 = __builtin_nontemporal_load(&col[min(i3, e1m1)]);
        int c4 = 0, c5 = 0;
        if (g4) c4 = __builtin_nontemporal_load(&col[min(i4, e1m1)]);
        if (g5) c5 = __builtin_nontemporal_load(&col[min(i5, e1m1)]);
        // all gathers issued back-to-back (progressive counted vmcnt waits)
        uint4 v0 = *reinterpret_cast<const uint4*>(&xs[c0 * 64 + 8 * l]);
        uint4 v1 = *reinterpret_cast<const uint4*>(&xs[c1 * 64 + 8 * l]);
        uint4 v2 = *reinterpret_cast<const uint4*>(&xs[c2 * 64 + 8 * l]);
        uint4 v3 = *reinterpret_cast<const uint4*>(&xs[c3 * 64 + 8 * l]);
        uint4 v4, v5;
        if (g4) v4 = *reinterpret_cast<const uint4*>(&xs[c4 * 64 + 8 * l]);
        if (g5) v5 = *reinterpret_cast<const uint4*>(&xs[c5 * 64 + 8 * l]);
        acc_bf8(v0, (i0 < e1) ? 1.f : 0.f, a);
        acc_bf8(v1, (i1 < e1) ? 1.f : 0.f, a);
        acc_bf8(v2, (i2 < e1) ? 1.f : 0.f, a);
        acc_bf8(v3, (i3 < e1) ? 1.f : 0.f, a);
        if (g4) acc_bf8(v4, (i4 < e1) ? 1.f : 0.f, a);
        if (g5) acc_bf8(v5, (i5 < e1) ? 1.f : 0.f, a);
    }
    acc_bf8(sv, (j == 0) ? 1.f : 0.f, a);   // self-loop term, counted once
#pragma unroll
    for (int k = 0; k < 8; ++k) {
        a[k] += __shfl_xor(a[k], 8);
        a[k] += __shfl_xor(a[k], 16);
        a[k] += __shfl_xor(a[k], 32);
    }
    if (j == 0) {
        float d = dinv[node];
        if constexpr (BF16OUT) {
            unsigned short* zh = reinterpret_cast<unsigned short*>(z);
            uint4 p;
            p.x = (unsigned)f2bf(a[0] * d) | ((unsigned)f2bf(a[1] * d) << 16);
            p.y = (unsigned)f2bf(a[2] * d) | ((unsigned)f2bf(a[3] * d) << 16);
            p.z = (unsigned)f2bf(a[4] * d) | ((unsigned)f2bf(a[5] * d) << 16);
            p.w = (unsigned)f2bf(a[6] * d) | ((unsigned)f2bf(a[7] * d) << 16);
            *reinterpret_cast<uint4*>(&zh[node * 64 + 8 * l]) = p;
        } else {
            float4 r0 = {a[0] * d, a[1] * d, a[2] * d, a[3] * d};
            float4 r1 = {a[4] * d, a[5] * d, a[6] * d, a[7] * d};
            *reinterpret_cast<float4*>(&z[node * 64 + 8 * l]) = r0;
            *reinterpret_cast<float4*>(&z[node * 64 + 8 * l + 4]) = r1;
        }
    }
}

// MFMA gemm: Y[N x M] = opt_scale(dinv) * opt_relu( X(bf16) @ W + opt_bias ).
// 64 rows/block (4 waves x 16). W^T staged ONCE per block into LDS as bf16
// [M][K+8] (pad -> <=2-way bank aliasing, free). A-frags straight from
// global (X is L2-resident: just written by the producer). One barrier.
// Frag layouts (gfx950 16x16x32 bf16): A row=lane&15, k=(lane>>4)*8+j;
// B col=lane&15, same k. C/D col=lane&15, row=(lane>>4)*4+reg [m89].
template <int K, int M, bool BIAS, bool RELU, bool SCALE, bool BF16OUT>
__global__ __launch_bounds__(256) void mgemm_kernel(
        const unsigned short* __restrict__ X, const float* __restrict__ W,
        const float* __restrict__ b, const float* __restrict__ dinv,
        float* __restrict__ Y, int nrows) {
    constexpr int KP = K + 8;                 // padded Wt row (bf16 elems)
    constexpr int NT = M / 16;                // n-tiles   (gemm2: 8, gemm3: 4)
    constexpr int KS = K / 32;                // k-steps   (gemm2: 2, gemm3: 4)
    __shared__ unsigned short Wt[M * KP];     // W^T bf16 (18.4 / 17.4 KB)
    int tid = threadIdx.x;
    for (int i = tid; i < K * M; i += 256) {  // stage W^T once
        int k = i / M, m = i % M;
        Wt[m * KP + k] = f2bf(W[i]);
    }
    __syncthreads();
    int wave = tid >> 6, lane = tid & 63;
    int row0 = blockIdx.x * 64 + wave * 16;
    int hl = lane >> 4, ll = lane & 15;
    // A-frags: row = row0+ll (clamped; tail stores masked), k = hl*8 .. +7
    int arow = min(row0 + ll, nrows - 1);
    bf16x8 afrag[KS];
#pragma unroll
    for (int ks = 0; ks < KS; ++ks)
        afrag[ks] = *reinterpret_cast<const bf16x8*>(&X[arow * K + ks * 32 + hl * 8]);
    f32x4 acc[NT];
#pragma unroll
    for (int nt = 0; nt < NT; ++nt) {
        float bv = BIAS ? b[nt * 16 + ll] : 0.0f;
        acc[nt] = {bv, bv, bv, bv};
    }
#pragma unroll
    for (int nt = 0; nt < NT; ++nt) {
#pragma unroll
        for (int ks = 0; ks < KS; ++ks) {
            bf16x8 bfrag = *reinterpret_cast<const bf16x8*>(
                &Wt[(nt * 16 + ll) * KP + ks * 32 + hl * 8]);
            acc[nt] = __builtin_amdgcn_mfma_f32_16x16x32_bf16(
                afrag[ks], bfrag, acc[nt], 0, 0, 0);
        }
    }
    // epilogue: D col=ll, row=hl*4+r
#pragma unroll
    for (int r = 0; r < 4; ++r) {
        int row = row0 + hl * 4 + r;
        if (row < nrows) {
            float d = SCALE ? dinv[row] : 1.0f;
#pragma unroll
            for (int nt = 0; nt < NT; ++nt) {
                float v = acc[nt][r];
                if constexpr (RELU) v = fmaxf(v, 0.0f);
                if constexpr (SCALE) v *= d;
                if constexpr (BF16OUT)
                    reinterpret_cast<unsigned short*>(Y)[row * M + nt * 16 + ll] = f2bf(v);
                else
                    Y[row * M + nt * 16 + ll] = v;
            }
        }
    }
}

// h3 = relu(z3 + b3); pool sums/counts per graph (R18 proven form).
#define POOL_NPB 128   // nodes per block (32 per wave, contiguous)
__global__ __launch_bounds__(256) void pool_kernel(
        const float* __restrict__ z3, const float* __restrict__ b3,
        const int* __restrict__ batch, float* __restrict__ sums,
        float* __restrict__ cntf, int n) {
    int wave = threadIdx.x >> 6;
    int lane = threadIdx.x & 63;   // feature index
    int node0 = blockIdx.x * POOL_NPB + wave * 32;
    int nodeEnd = min(node0 + 32, n);
    if (node0 >= n) return;
    float bias = b3[lane];
    float acc = 0.0f, cnt = 0.0f;
    int curg = -1;
    for (int node = node0; node < nodeEnd; ++node) {
        int g = batch[node];               // wave-uniform (lane = feature)
        if (g != curg) {                   // wave-uniform branch
            if (curg >= 0) {
                atomicAdd(&sums[curg * 64 + lane], acc);
                if (lane == 0) atomicAdd(&cntf[curg], cnt);
            }
            curg = g; acc = 0.0f; cnt = 0.0f;
        }
        acc += fmaxf(__builtin_nontemporal_load(&z3[node * 64 + lane]) + bias, 0.0f);
        cnt += 1.0f;
    }
    if (curg >= 0) {
        atomicAdd(&sums[curg * 64 + lane], acc);
        if (lane == 0) atomicAdd(&cntf[curg], cnt);
    }
}

// per-graph: g = sums/max(cnt,1); hid = relu(g@Wl1+bl1); out = hid@Wl2+bl2
__global__ void mlp_kernel(const float* __restrict__ sums, const float* __restrict__ cntf,
                           const float* __restrict__ Wl1, const float* __restrict__ bl1,
                           const float* __restrict__ Wl2, const float* __restrict__ bl2,
                           float* __restrict__ out) {
    __shared__ float gv[64];
    __shared__ float hid[32];
    int g = blockIdx.x, t = threadIdx.x;
    float denom = fmaxf(cntf[g], 1.0f);
    gv[t] = sums[g * 64 + t] / denom;
    __syncthreads();
    if (t < 32) {
        float a = bl1[t];
#pragma unroll
        for (int k = 0; k < 64; ++k) a += gv[k] * Wl1[k * 32 + t];
        hid[t] = fmaxf(a, 0.0f);
    }
    __syncthreads();
    if (t == 0) {
        float o = bl2[0];
#pragma unroll
        for (int k = 0; k < 32; ++k) o += hid[k] * Wl2[k];
        out[g] = o;
    }
}

extern "C" void kernel_launch(void* const* d_in, const int* in_sizes, int n_in,
                              void* d_out, int out_size, void* d_ws, size_t ws_size,
                              hipStream_t stream) {
    const float* x   = (const float*)d_in[0];
    const int* ei    = (const int*)d_in[1];
    const int* batch = (const int*)d_in[2];
    const float* W1  = (const float*)d_in[3];
    const float* b1  = (const float*)d_in[4];
    const float* W2  = (const float*)d_in[5];
    const float* b2  = (const float*)d_in[6];
    const float* W3  = (const float*)d_in[7];
    const float* b3  = (const float*)d_in[8];
    const float* Wl1 = (const float*)d_in[9];
    const float* bl1 = (const float*)d_in[10];
    const float* Wl2 = (const float*)d_in[11];
    const float* bl2 = (const float*)d_in[12];
    float* out = (float*)d_out;

    const int N = N_NODES;
    const int E = in_sizes[1] / 2;   // 3.2M
    const int* src = ei;
    const int* dst = ei + E;

    char* ws = (char*)d_ws;
    float* sums    = (float*)(ws + OFF_SUMS);
    float* cntf    = (float*)(ws + OFF_CNTF);
    int*   hist    = (int*)(ws + OFF_HIST);
    int*   bsum    = (int*)(ws + OFF_BSUM);
    int*   row_ptr = (int*)(ws + OFF_ROWPTR);
    float* dinv    = (float*)(ws + OFF_DINV);
    int*   col     = (int*)(ws + OFF_COL);
    unsigned short* xs1 = (unsigned short*)(ws + OFF_XS1);   // bf16
    float* bufQ    = (float*)(ws + OFF_BUFQ);   // bf16 xs2, later fp32 z3
    float* bufR    = (float*)(ws + OFF_BUFR);   // bf16 z2, later bf16 ys
    float* bufP    = (float*)(ws + OFF_BUFP);   // bf16 h2
    int*   packed  = (int*)(ws + OFF_PAIRS);    // aliases bufP (dead before h2)

    // CSR build: hist(+zero) -> scanA -> bin -> csr(+xs1 scale, LDS-staged col)
    int epb = (E + NBLK - 1) / NBLK;   // 12500
    hist_kernel<<<NBLK, 256, 0, stream>>>(dst, hist, (int*)ws, E, epb);
    scanhA_kernel<<<SCAN_BLKS, 1024, 0, stream>>>(hist, bsum);
    bin_kernel<<<NBLK, 256, 0, stream>>>(src, dst, hist, bsum, packed, E, epb);
    csr_kernel<<<NB_BUCKETS, 512, 0, stream>>>(packed, hist, bsum, x,
                                               row_ptr, dinv, xs1, col, E);

    // Layer 1 (agg + gemm1 fused): xs2(bf16) = dinv*relu((agg xs1)@W1+b1)
    agg8g1_kernel<<<(N + 3) / 4, 256, 0, stream>>>(xs1, row_ptr, col, dinv, W1, b1,
                                                   (unsigned short*)bufQ, N);

    // Layer 2: z2(bf16) = agg_bf16(xs2) ; h2(bf16) = relu(z2@W2+b2)  [MFMA]
    agg64bf_kernel<true><<<(N + 3) / 4, 256, 0, stream>>>(
        (const unsigned short*)bufQ, row_ptr, col, dinv, bufR, 0, N);
    mgemm_kernel<64, 128, true, true, false, true><<<1563, 256, 0, stream>>>(
        (const unsigned short*)bufR, W2, b2, nullptr, bufP, N);

    // Layer 3: ys(bf16) = dinv*(h2@W3) ; z3(fp32) = agg_bf16(ys)      [MFMA]
    mgemm_kernel<128, 64, false, false, true, true><<<1563, 256, 0, stream>>>(
        (const unsigned short*)bufP, W3, nullptr, dinv, bufR, N);
    agg64bf_kernel<false><<<(N + 3) / 4, 256, 0, stream>>>(
        (const unsigned short*)bufR, row_ptr, col, dinv, bufQ, 0, N);

    // Pool + MLP head
    pool_kernel<<<(N + POOL_NPB - 1) / POOL_NPB, 256, 0, stream>>>(bufQ, b3, batch, sums, cntf, N);
    mlp_kernel<<<N_GRAPHS, 64, 0, stream>>>(sums, cntf, Wl1, bl1, Wl2, bl2, out);
}